// Round 1
// baseline (1087.218 us; speedup 1.0000x reference)
//
#include <hip/hip_runtime.h>

// ---------------------------------------------------------------------------
// DotProductAttention: out = softmax(mask(Q K^T * scale)) @ V
//                          + (q_mult @ (kv_mult^T @ V)) / (||q_mult kv_mult^T||_F + eps)
// B=2 H=16 BH=32 L=2048 D=128, f32 in/out, bf16 MFMA internally.
// ---------------------------------------------------------------------------

typedef __attribute__((ext_vector_type(8))) __bf16 bf16x8;
typedef __attribute__((ext_vector_type(4))) float f32x4;
typedef __attribute__((ext_vector_type(4))) unsigned int u32x4;

#define DEV static __device__ __forceinline__

constexpr int LL = 2048, DD = 128, BH = 32;
constexpr float SCALE = 0.08838834764831845f;  // 1/sqrt(128)
constexpr float NEGV = -1e6f;

DEV unsigned short f2b(float x) {  // f32 -> bf16 RNE
  unsigned u = __builtin_bit_cast(unsigned, x);
  u += 0x7fffu + ((u >> 16) & 1u);
  return (unsigned short)(u >> 16);
}
DEV unsigned pk2(float lo, float hi) {
  return (unsigned)f2b(lo) | ((unsigned)f2b(hi) << 16);
}

DEV f32x4 mfma16(bf16x8 a, bf16x8 b, f32x4 c) {
  return __builtin_amdgcn_mfma_f32_16x16x32_bf16(a, b, c, 0, 0, 0);
}

// LDS byte-address swizzles (guide G4: XOR row bits into 16B-slot bits)
DEV int swzK(int row, int col) { return ((row * 128 + col) * 2) ^ ((row & 7) << 4); }
DEV int swzV(int d, int k)     { return ((d * 64 + k) * 2)     ^ ((d & 7) << 4); }
DEV int swzP(int row, int col) { return ((row * 64 + col) * 2) ^ ((row & 7) << 4); }

// --------------------------- f32 -> bf16 convert ---------------------------
__global__ void k_convert(const float* __restrict__ src, unsigned short* __restrict__ dst, int n4) {
  int i = blockIdx.x * blockDim.x + threadIdx.x;
  int stride = gridDim.x * blockDim.x;
  for (; i < n4; i += stride) {
    float4 v = ((const float4*)src)[i];
    ushort4 o;
    o.x = f2b(v.x); o.y = f2b(v.y); o.z = f2b(v.z); o.w = f2b(v.w);
    ((ushort4*)dst)[i] = o;
  }
}

// ------------------- Gram matrices: G = A^T A per batch --------------------
// grid (16 iblk, 4 lchunk, 4 = which*2+b), block 128.  G zero-initialized.
__global__ void k_gram(const float* __restrict__ qm, const float* __restrict__ km,
                       float* __restrict__ Gq, float* __restrict__ Gk) {
  int which = blockIdx.z >> 1, b = blockIdx.z & 1;
  const float* A = (which ? km : qm) + (size_t)b * LL * DD;
  float* G = (which ? Gk : Gq) + (size_t)b * DD * DD;
  int i0 = blockIdx.x * 8;
  int l0 = blockIdx.y * 512;
  __shared__ float s[32][128];
  float acc[8];
#pragma unroll
  for (int i = 0; i < 8; ++i) acc[i] = 0.f;
  for (int ch = 0; ch < 16; ++ch) {
    __syncthreads();
    for (int rr = 0; rr < 32; ++rr)
      s[rr][threadIdx.x] = A[(size_t)(l0 + ch * 32 + rr) * DD + threadIdx.x];
    __syncthreads();
    for (int ll = 0; ll < 32; ++ll) {
      float aj = s[ll][threadIdx.x];
#pragma unroll
      for (int ii = 0; ii < 8; ++ii) acc[ii] += s[ll][i0 + ii] * aj;
    }
  }
#pragma unroll
  for (int ii = 0; ii < 8; ++ii)
    atomicAdd(&G[(size_t)(i0 + ii) * DD + threadIdx.x], acc[ii]);
}

// ------------------- fro[b] = sqrt(sum Gq .* Gk) ---------------------------
__global__ void k_fro(const float* __restrict__ Gq, const float* __restrict__ Gk,
                      float* __restrict__ fro) {
  int b = blockIdx.x;
  const float* gq = Gq + (size_t)b * DD * DD;
  const float* gk = Gk + (size_t)b * DD * DD;
  float acc = 0.f;
  for (int i = threadIdx.x; i < DD * DD; i += 256) acc += gq[i] * gk[i];
#pragma unroll
  for (int m = 32; m; m >>= 1) acc += __shfl_xor(acc, m);
  __shared__ float sbuf[4];
  if ((threadIdx.x & 63) == 0) sbuf[threadIdx.x >> 6] = acc;
  __syncthreads();
  if (threadIdx.x == 0) fro[b] = sqrtf(sbuf[0] + sbuf[1] + sbuf[2] + sbuf[3]);
}

// ------------------- M[bh] = kv_mult[b]^T @ V[bh]  (128x128, f32) ----------
// grid (32 bh, 16 lc), block 256.  M zero-initialized; atomic accumulate.
__global__ void k_M(const float* __restrict__ km, const float* __restrict__ Vf,
                    float* __restrict__ M) {
  int bh = blockIdx.x, b = bh >> 4;
  int l0 = blockIdx.y * 128;
  __shared__ float skv[16][128];
  __shared__ float sv[16][128];
  int j = threadIdx.x & 127, i0 = (threadIdx.x >> 7) * 64;
  float acc[64];
#pragma unroll
  for (int i = 0; i < 64; ++i) acc[i] = 0.f;
  for (int c = 0; c < 8; ++c) {
    __syncthreads();
    for (int x = 0; x < 8; ++x) {
      int idx = x * 256 + threadIdx.x;
      int rr = idx >> 7, cc = idx & 127;
      skv[rr][cc] = km[(size_t)(b * LL + l0 + c * 16 + rr) * DD + cc];
      sv[rr][cc]  = Vf[(size_t)(bh * LL + l0 + c * 16 + rr) * DD + cc];
    }
    __syncthreads();
    for (int ll = 0; ll < 16; ++ll) {
      float v = sv[ll][j];
#pragma unroll
      for (int ii = 0; ii < 64; ++ii) acc[ii] += skv[ll][i0 + ii] * v;
    }
  }
#pragma unroll
  for (int ii = 0; ii < 64; ++ii)
    atomicAdd(&M[(size_t)bh * DD * DD + (size_t)(i0 + ii) * DD + j], acc[ii]);
}

// ------------------------------ flash attention ----------------------------
// grid (16 qtile, 32 bh), block 256 (4 waves, 32 q-rows/wave), KV tile 64.
template <bool F32IN>
__global__ void k_flash(const unsigned short* __restrict__ Qb,
                        const unsigned short* __restrict__ Kb,
                        const unsigned short* __restrict__ Vb,
                        const float* __restrict__ Qf,
                        const float* __restrict__ Kf,
                        const float* __restrict__ Vf,
                        const int* __restrict__ vlens,
                        float* __restrict__ out) {
  __shared__ __align__(16) unsigned short Kt[64 * 128];   // [k][d], swizzled
  __shared__ __align__(16) unsigned short Vt[128 * 64];   // [d][k] transposed, swizzled
  __shared__ __align__(16) unsigned short Pt[4][32 * 64]; // per-wave P, swizzled

  const int bh = blockIdx.y;
  const int qbase = blockIdx.x * 128;
  const int tid = threadIdx.x;
  const int w = tid >> 6, lane = tid & 63;
  const int r = lane & 15, g = lane >> 4;
  const int vlen = vlens[bh];
  const size_t base = (size_t)bh * LL * DD;

  // Q fragments (A-layout: row = lane&15, k = (lane>>4)*8 + j)
  bf16x8 aQ[2][4];
#pragma unroll
  for (int rs = 0; rs < 2; ++rs)
#pragma unroll
    for (int c = 0; c < 4; ++c) {
      int row = qbase + w * 32 + rs * 16 + r;
      int col = 32 * c + 8 * g;
      if (!F32IN) {
        aQ[rs][c] = *(const bf16x8*)(Qb + base + (size_t)row * DD + col);
      } else {
        const float* p = Qf + base + (size_t)row * DD + col;
        float4 x0 = *(const float4*)p, x1 = *(const float4*)(p + 4);
        union { unsigned us[4]; bf16x8 v; } u;
        u.us[0] = pk2(x0.x, x0.y); u.us[1] = pk2(x0.z, x0.w);
        u.us[2] = pk2(x1.x, x1.y); u.us[3] = pk2(x1.z, x1.w);
        aQ[rs][c] = u.v;
      }
    }

  f32x4 o_[2][8];
  f32x4 m_[2], l_[2];
#pragma unroll
  for (int rs = 0; rs < 2; ++rs) {
#pragma unroll
    for (int nb = 0; nb < 8; ++nb) o_[rs][nb] = f32x4{0.f, 0.f, 0.f, 0.f};
    m_[rs] = f32x4{-3e38f, -3e38f, -3e38f, -3e38f};
    l_[rs] = f32x4{0.f, 0.f, 0.f, 0.f};
  }

  const int NT = LL / 64;
  int nt = (vlen == 0) ? NT : ((vlen + 63) >> 6);
  if (nt > NT) nt = NT;

  for (int t = 0; t < nt; ++t) {
    const int kbase = t * 64;
    __syncthreads();
    // ---- stage K tile (row-major, swizzled) ----
#pragma unroll
    for (int it = 0; it < 4; ++it) {
      int idx = it * 256 + tid;
      int kk = idx >> 4, d8 = (idx & 15) * 8;
      u32x4 val;
      if (!F32IN) {
        val = *(const u32x4*)(Kb + base + (size_t)(kbase + kk) * DD + d8);
      } else {
        const float* p = Kf + base + (size_t)(kbase + kk) * DD + d8;
        float4 x0 = *(const float4*)p, x1 = *(const float4*)(p + 4);
        val.x = pk2(x0.x, x0.y); val.y = pk2(x0.z, x0.w);
        val.z = pk2(x1.x, x1.y); val.w = pk2(x1.z, x1.w);
      }
      *(u32x4*)((char*)&Kt[0] + swzK(kk, d8)) = val;
    }
    // ---- stage V tile transposed ([d][k], swizzled), 2x2 micro-blocks ----
#pragma unroll
    for (int i2 = 0; i2 < 4; ++i2)
#pragma unroll
      for (int it = 0; it < 2; ++it) {
        int kp = (lane & 7) + 8 * i2;
        int d = 2 * (lane >> 3) + 16 * (2 * w + it);
        int row0 = kbase + 2 * kp;
        unsigned a, b2;
        if (!F32IN) {
          a  = *(const unsigned*)(Vb + base + (size_t)row0 * DD + d);
          b2 = *(const unsigned*)(Vb + base + (size_t)(row0 + 1) * DD + d);
        } else {
          float2 va = *(const float2*)(Vf + base + (size_t)row0 * DD + d);
          float2 vb = *(const float2*)(Vf + base + (size_t)(row0 + 1) * DD + d);
          a = pk2(va.x, va.y); b2 = pk2(vb.x, vb.y);
        }
        unsigned w0 = (a & 0xffffu) | (b2 << 16);
        unsigned w1 = (a >> 16) | (b2 & 0xffff0000u);
        *(unsigned*)((char*)&Vt[0] + swzV(d, 2 * kp)) = w0;
        *(unsigned*)((char*)&Vt[0] + swzV(d + 1, 2 * kp)) = w1;
      }
    __syncthreads();

    // ---- S = Q K^T (D-layout: col=lane&15, row=(lane>>4)*4+reg) ----
    f32x4 s[2][4];
#pragma unroll
    for (int rs = 0; rs < 2; ++rs)
#pragma unroll
      for (int cb = 0; cb < 4; ++cb) s[rs][cb] = f32x4{0.f, 0.f, 0.f, 0.f};
#pragma unroll
    for (int cb = 0; cb < 4; ++cb)
#pragma unroll
      for (int c = 0; c < 4; ++c) {
        bf16x8 bk = *(const bf16x8*)((char*)&Kt[0] + swzK(16 * cb + r, 32 * c + 8 * g));
        s[0][cb] = mfma16(aQ[0][c], bk, s[0][cb]);
        s[1][cb] = mfma16(aQ[1][c], bk, s[1][cb]);
      }

    // ---- mask + online softmax + P -> LDS ----
#pragma unroll
    for (int rs = 0; rs < 2; ++rs) {
      f32x4 ps[4];
#pragma unroll
      for (int cb = 0; cb < 4; ++cb) {
        bool valid = (kbase + 16 * cb + r) < vlen;
#pragma unroll
        for (int q = 0; q < 4; ++q)
          ps[cb][q] = valid ? s[rs][cb][q] * SCALE : NEGV;
      }
      f32x4 rm = ps[0];
#pragma unroll
      for (int cb = 1; cb < 4; ++cb)
#pragma unroll
        for (int q = 0; q < 4; ++q) rm[q] = fmaxf(rm[q], ps[cb][q]);
#pragma unroll
      for (int q = 0; q < 4; ++q) {
        float v = rm[q];
        v = fmaxf(v, __shfl_xor(v, 1));
        v = fmaxf(v, __shfl_xor(v, 2));
        v = fmaxf(v, __shfl_xor(v, 4));
        v = fmaxf(v, __shfl_xor(v, 8));
        rm[q] = v;
      }
      f32x4 mnew, alpha, rsum;
#pragma unroll
      for (int q = 0; q < 4; ++q) {
        mnew[q] = fmaxf(m_[rs][q], rm[q]);
        alpha[q] = __expf(m_[rs][q] - mnew[q]);
        rsum[q] = 0.f;
      }
      f32x4 pw[4];
#pragma unroll
      for (int cb = 0; cb < 4; ++cb)
#pragma unroll
        for (int q = 0; q < 4; ++q) {
          float pv = __expf(ps[cb][q] - mnew[q]);
          pw[cb][q] = pv;
          rsum[q] += pv;
        }
#pragma unroll
      for (int q = 0; q < 4; ++q) {
        float v = rsum[q];
        v += __shfl_xor(v, 1);
        v += __shfl_xor(v, 2);
        v += __shfl_xor(v, 4);
        v += __shfl_xor(v, 8);
        rsum[q] = v;
      }
#pragma unroll
      for (int q = 0; q < 4; ++q) l_[rs][q] = l_[rs][q] * alpha[q] + rsum[q];
      m_[rs] = mnew;
#pragma unroll
      for (int nb = 0; nb < 8; ++nb)
#pragma unroll
        for (int q = 0; q < 4; ++q) o_[rs][nb][q] *= alpha[q];
#pragma unroll
      for (int cb = 0; cb < 4; ++cb)
#pragma unroll
        for (int q = 0; q < 4; ++q)
          *(unsigned short*)((char*)&Pt[w][0] + swzP(rs * 16 + 4 * g + q, 16 * cb + r)) =
              f2b(pw[cb][q]);
    }

    // ---- O += P @ V ----
    bf16x8 ap[2][2];
#pragma unroll
    for (int rs = 0; rs < 2; ++rs)
#pragma unroll
      for (int c2 = 0; c2 < 2; ++c2)
        ap[rs][c2] = *(const bf16x8*)((char*)&Pt[w][0] + swzP(rs * 16 + r, 32 * c2 + 8 * g));
#pragma unroll
    for (int nb = 0; nb < 8; ++nb)
#pragma unroll
      for (int c2 = 0; c2 < 2; ++c2) {
        bf16x8 bv = *(const bf16x8*)((char*)&Vt[0] + swzV(16 * nb + r, 32 * c2 + 8 * g));
        o_[0][nb] = mfma16(ap[0][c2], bv, o_[0][nb]);
        o_[1][nb] = mfma16(ap[1][c2], bv, o_[1][nb]);
      }
  }

  // ---- epilogue: normalize and store ----
#pragma unroll
  for (int rs = 0; rs < 2; ++rs) {
    f32x4 rcp;
#pragma unroll
    for (int q = 0; q < 4; ++q) rcp[q] = 1.f / l_[rs][q];
#pragma unroll
    for (int nb = 0; nb < 8; ++nb)
#pragma unroll
      for (int q = 0; q < 4; ++q) {
        int row = qbase + w * 32 + rs * 16 + 4 * g + q;
        out[base + (size_t)row * DD + 16 * nb + r] = o_[rs][nb][q] * rcp[q];
      }
  }
}

// ---------------- out += q_mult @ M / (fro + eps)  -------------------------
// grid (16 ltile, 32 bh), block 256.
__global__ void k_multadd(const float* __restrict__ qm, const float* __restrict__ M,
                          const float* __restrict__ fro, float* __restrict__ out) {
  int bh = blockIdx.y, b = bh >> 4;
  int l = blockIdx.x * 128 + (threadIdx.x & 127);
  int dh = (threadIdx.x >> 7) * 64;
  float inv = 1.0f / (fro[b] + 1e-5f);
  const float* qrow = qm + ((size_t)b * LL + l) * DD;
  const float* Mb = M + (size_t)bh * DD * DD + dh;
  float acc[64];
#pragma unroll
  for (int i = 0; i < 64; ++i) acc[i] = 0.f;
  for (int k = 0; k < 128; ++k) {
    float qv = qrow[k];
    const float4* m4 = (const float4*)(Mb + (size_t)k * DD);
#pragma unroll
    for (int i = 0; i < 16; ++i) {
      float4 mm = m4[i];
      acc[4 * i + 0] += qv * mm.x;
      acc[4 * i + 1] += qv * mm.y;
      acc[4 * i + 2] += qv * mm.z;
      acc[4 * i + 3] += qv * mm.w;
    }
  }
  float* op = out + ((size_t)bh * LL + l) * DD + dh;
#pragma unroll
  for (int i = 0; i < 16; ++i) {
    float4 ov = ((float4*)op)[i];
    ov.x += acc[4 * i + 0] * inv;
    ov.y += acc[4 * i + 1] * inv;
    ov.z += acc[4 * i + 2] * inv;
    ov.w += acc[4 * i + 3] * inv;
    ((float4*)op)[i] = ov;
  }
}

// ---------------------------------------------------------------------------
extern "C" void kernel_launch(void* const* d_in, const int* in_sizes, int n_in,
                              void* d_out, int out_size, void* d_ws, size_t ws_size,
                              hipStream_t stream) {
  (void)in_sizes; (void)n_in; (void)out_size;
  const float* Q  = (const float*)d_in[0];
  const float* K  = (const float*)d_in[1];
  const float* V  = (const float*)d_in[2];
  const float* qm = (const float*)d_in[3];
  const float* km = (const float*)d_in[4];
  const int* vl   = (const int*)d_in[5];
  float* out = (float*)d_out;

  char* ws = (char*)d_ws;
  const size_t off_M  = 0;                       // 32*128*128*4 = 2,097,152
  const size_t off_Gq = 2097152;                 // 2*128*128*4  =   131,072
  const size_t off_Gk = off_Gq + 131072;
  const size_t off_fro = off_Gk + 131072;        // 8B (+pad)
  const size_t off_bf = off_fro + 256;
  const size_t nElem = (size_t)BH * LL * DD;
  const size_t szbf = nElem * 2;
  bool bf_fits = ws_size >= off_bf + 3 * szbf;

  float* Mw  = (float*)(ws + off_M);
  float* Gq  = (float*)(ws + off_Gq);
  float* Gk  = (float*)(ws + off_Gk);
  float* fro = (float*)(ws + off_fro);
  unsigned short* Qb = (unsigned short*)(ws + off_bf);
  unsigned short* Kb = Qb + nElem;
  unsigned short* Vb = Kb + nElem;

  hipMemsetAsync(d_ws, 0, off_bf, stream);

  if (bf_fits) {
    int n4 = (int)(nElem / 4);
    k_convert<<<2048, 256, 0, stream>>>(Q, Qb, n4);
    k_convert<<<2048, 256, 0, stream>>>(K, Kb, n4);
    k_convert<<<2048, 256, 0, stream>>>(V, Vb, n4);
  }
  k_gram<<<dim3(16, 4, 4), 128, 0, stream>>>(qm, km, Gq, Gk);
  k_fro<<<2, 256, 0, stream>>>(Gq, Gk, fro);
  k_M<<<dim3(32, 16), 256, 0, stream>>>(km, V, Mw);

  if (bf_fits)
    k_flash<false><<<dim3(16, 32), 256, 0, stream>>>(Qb, Kb, Vb, Q, K, V, vl, out);
  else
    k_flash<true><<<dim3(16, 32), 256, 0, stream>>>(Qb, Kb, Vb, Q, K, V, vl, out);

  k_multadd<<<dim3(16, 32), 256, 0, stream>>>(qm, Mw, fro, out);
}

// Round 2
// 848.653 us; speedup vs baseline: 1.2811x; 1.2811x over previous
//
#include <hip/hip_runtime.h>

// ---------------------------------------------------------------------------
// DotProductAttention: out = softmax(mask(Q K^T * scale)) @ V
//                          + (q_mult @ (kv_mult^T @ V)) / (||q_mult kv_mult^T||_F + eps)
// B=2 H=16 BH=32 L=2048 D=128, f32 in/out, bf16 MFMA internally.
// v2: f32-direct flash with coalesced staging + register double-buffering.
// ---------------------------------------------------------------------------

typedef __attribute__((ext_vector_type(8))) __bf16 bf16x8;
typedef __attribute__((ext_vector_type(4))) float f32x4;
typedef __attribute__((ext_vector_type(4))) unsigned int u32x4;

#define DEV static __device__ __forceinline__

constexpr int LL = 2048, DD = 128, BH = 32;
constexpr float SCALE = 0.08838834764831845f;  // 1/sqrt(128)
constexpr float NEGV = -1e6f;

DEV unsigned short f2b(float x) {  // f32 -> bf16 RNE
  unsigned u = __builtin_bit_cast(unsigned, x);
  u += 0x7fffu + ((u >> 16) & 1u);
  return (unsigned short)(u >> 16);
}
DEV unsigned pk2(float lo, float hi) {
  return (unsigned)f2b(lo) | ((unsigned)f2b(hi) << 16);
}
DEV f32x4 mfma16(bf16x8 a, bf16x8 b, f32x4 c) {
  return __builtin_amdgcn_mfma_f32_16x16x32_bf16(a, b, c, 0, 0, 0);
}

// LDS byte-address swizzles
DEV int swzK(int row, int col) { return ((row * 128 + col) * 2) ^ ((row & 7) << 4); }
DEV int swzV(int d, int k) {
  return ((d * 64 + k) * 2) ^ ((((d & 7) ^ ((d >> 3) & 7))) << 4);
}
DEV int swzP(int row, int col) { return ((row * 64 + col) * 2) ^ ((row & 7) << 4); }

// ------------------- Gram matrices: G = A^T A per batch --------------------
__global__ void k_gram(const float* __restrict__ qm, const float* __restrict__ km,
                       float* __restrict__ Gq, float* __restrict__ Gk) {
  int which = blockIdx.z >> 1, b = blockIdx.z & 1;
  const float* A = (which ? km : qm) + (size_t)b * LL * DD;
  float* G = (which ? Gk : Gq) + (size_t)b * DD * DD;
  int i0 = blockIdx.x * 8;
  int l0 = blockIdx.y * 512;
  __shared__ float s[32][128];
  float acc[8];
#pragma unroll
  for (int i = 0; i < 8; ++i) acc[i] = 0.f;
  for (int ch = 0; ch < 16; ++ch) {
    __syncthreads();
    for (int rr = 0; rr < 32; ++rr)
      s[rr][threadIdx.x] = A[(size_t)(l0 + ch * 32 + rr) * DD + threadIdx.x];
    __syncthreads();
    for (int ll = 0; ll < 32; ++ll) {
      float aj = s[ll][threadIdx.x];
#pragma unroll
      for (int ii = 0; ii < 8; ++ii) acc[ii] += s[ll][i0 + ii] * aj;
    }
  }
#pragma unroll
  for (int ii = 0; ii < 8; ++ii)
    atomicAdd(&G[(size_t)(i0 + ii) * DD + threadIdx.x], acc[ii]);
}

// ------------------- fro[b] = sqrt(sum Gq .* Gk) ---------------------------
__global__ void k_fro(const float* __restrict__ Gq, const float* __restrict__ Gk,
                      float* __restrict__ fro) {
  int b = blockIdx.x;
  const float* gq = Gq + (size_t)b * DD * DD;
  const float* gk = Gk + (size_t)b * DD * DD;
  float acc = 0.f;
  for (int i = threadIdx.x; i < DD * DD; i += 256) acc += gq[i] * gk[i];
#pragma unroll
  for (int m = 32; m; m >>= 1) acc += __shfl_xor(acc, m);
  __shared__ float sbuf[4];
  if ((threadIdx.x & 63) == 0) sbuf[threadIdx.x >> 6] = acc;
  __syncthreads();
  if (threadIdx.x == 0) fro[b] = sqrtf(sbuf[0] + sbuf[1] + sbuf[2] + sbuf[3]);
}

// ------------------- M[bh] = kv_mult[b]^T @ V[bh]  (128x128, f32) ----------
// grid (32 bh, 16 lc), block 256 = (32 j-blocks x 8 i-blocks). register-blocked.
__global__ void k_M(const float* __restrict__ km, const float* __restrict__ Vf,
                    float* __restrict__ M) {
  int bh = blockIdx.x, b = bh >> 4;
  int l0 = blockIdx.y * 128;
  __shared__ float skv[16][128];
  __shared__ float sv[16][128];
  int j0 = (threadIdx.x & 31) * 4;
  int i0 = (threadIdx.x >> 5) * 16;
  float acc[16][4];
#pragma unroll
  for (int i = 0; i < 16; ++i)
#pragma unroll
    for (int q = 0; q < 4; ++q) acc[i][q] = 0.f;
  for (int c = 0; c < 8; ++c) {
    __syncthreads();
    for (int x = 0; x < 8; ++x) {
      int idx = x * 256 + threadIdx.x;
      int rr = idx >> 7, cc = idx & 127;
      skv[rr][cc] = km[(size_t)(b * LL + l0 + c * 16 + rr) * DD + cc];
      sv[rr][cc]  = Vf[(size_t)(bh * LL + l0 + c * 16 + rr) * DD + cc];
    }
    __syncthreads();
    for (int ll = 0; ll < 16; ++ll) {
      float a0 = sv[ll][j0], a1 = sv[ll][j0 + 1];
      float a2 = sv[ll][j0 + 2], a3 = sv[ll][j0 + 3];
#pragma unroll
      for (int ii = 0; ii < 16; ++ii) {
        float kv = skv[ll][i0 + ii];
        acc[ii][0] += kv * a0;
        acc[ii][1] += kv * a1;
        acc[ii][2] += kv * a2;
        acc[ii][3] += kv * a3;
      }
    }
  }
#pragma unroll
  for (int ii = 0; ii < 16; ++ii)
#pragma unroll
    for (int q = 0; q < 4; ++q)
      atomicAdd(&M[(size_t)bh * DD * DD + (size_t)(i0 + ii) * DD + j0 + q], acc[ii][q]);
}

// ------------------------------ flash attention ----------------------------
// grid (32 bh, 16 qtile), block 256 (4 waves, 32 q-rows/wave), KV tile 64.
// f32 inputs packed to bf16 inline; register double-buffered staging.
__global__ __launch_bounds__(256, 2)
void k_flash(const float* __restrict__ Qf, const float* __restrict__ Kf,
             const float* __restrict__ Vf, const int* __restrict__ vlens,
             float* __restrict__ out) {
  __shared__ __align__(16) unsigned short Kt[64 * 128];   // [k][d], swizzled
  __shared__ __align__(16) unsigned short Vt[128 * 64];   // [d][k] transposed, swizzled
  __shared__ __align__(16) unsigned short Pt[4][32 * 64]; // per-wave P, swizzled

  const int bh = blockIdx.x;       // bh on grid.x: all 16 q-tiles of a head -> same XCD
  const int qbase = blockIdx.y * 128;
  const int tid = threadIdx.x;
  const int w = tid >> 6, lane = tid & 63;
  const int r = lane & 15, g = lane >> 4;
  const int vlen = vlens[bh];
  const size_t base = (size_t)bh * LL * DD;

  // ---- Q fragments (A-layout: row = lane&15, k = (lane>>4)*8 + j) ----
  bf16x8 aQ[2][4];
#pragma unroll
  for (int rs = 0; rs < 2; ++rs)
#pragma unroll
    for (int c = 0; c < 4; ++c) {
      int row = qbase + w * 32 + rs * 16 + r;
      int col = 32 * c + 8 * g;
      const float* p = Qf + base + (size_t)row * DD + col;
      float4 x0 = *(const float4*)p, x1 = *(const float4*)(p + 4);
      union { unsigned us[4]; bf16x8 v; } u;
      u.us[0] = pk2(x0.x, x0.y); u.us[1] = pk2(x0.z, x0.w);
      u.us[2] = pk2(x1.x, x1.y); u.us[3] = pk2(x1.z, x1.w);
      aQ[rs][c] = u.v;
    }

  f32x4 o_[2][8];
  f32x4 m_[2], l_[2];
#pragma unroll
  for (int rs = 0; rs < 2; ++rs) {
#pragma unroll
    for (int nb = 0; nb < 8; ++nb) o_[rs][nb] = f32x4{0.f, 0.f, 0.f, 0.f};
    m_[rs] = f32x4{-3e38f, -3e38f, -3e38f, -3e38f};
    l_[rs] = f32x4{0.f, 0.f, 0.f, 0.f};
  }

  const int NT = LL / 64;
  int nt = (vlen == 0) ? NT : ((vlen + 63) >> 6);
  if (nt > NT) nt = NT;

  // ---- staging registers (double buffer through regs) ----
  float kA[2][16];       // K: 2 iters x 16 consecutive floats (64B/lane, coalesced)
  float vA[4][4], vB[4][4];  // V: 4 iters x two adjacent rows x 4 floats

  auto LOAD = [&](int t) {
    const float* kb = Kf + base + (size_t)(t * 64) * DD;
    const float* vb = Vf + base + (size_t)(t * 64) * DD;
#pragma unroll
    for (int it = 0; it < 2; ++it) {
      int idx = it * 256 + tid;
      int kr = idx >> 3, c16 = (idx & 7) * 16;
      const float* p = kb + (size_t)kr * DD + c16;
      *(float4*)&kA[it][0]  = *(const float4*)(p);
      *(float4*)&kA[it][4]  = *(const float4*)(p + 4);
      *(float4*)&kA[it][8]  = *(const float4*)(p + 8);
      *(float4*)&kA[it][12] = *(const float4*)(p + 12);
    }
#pragma unroll
    for (int it = 0; it < 4; ++it) {
      int k0 = it * 16 + 4 * w + 2 * (lane >> 5);
      int d4 = (lane & 31) * 4;
      *(float4*)&vA[it][0] = *(const float4*)(vb + (size_t)k0 * DD + d4);
      *(float4*)&vB[it][0] = *(const float4*)(vb + (size_t)(k0 + 1) * DD + d4);
    }
  };

  auto WRITE = [&]() {
#pragma unroll
    for (int it = 0; it < 2; ++it) {
      int idx = it * 256 + tid;
      int kr = idx >> 3, c16 = (idx & 7) * 16;
      u32x4 w0, w1;
      w0.x = pk2(kA[it][0], kA[it][1]);  w0.y = pk2(kA[it][2], kA[it][3]);
      w0.z = pk2(kA[it][4], kA[it][5]);  w0.w = pk2(kA[it][6], kA[it][7]);
      w1.x = pk2(kA[it][8], kA[it][9]);  w1.y = pk2(kA[it][10], kA[it][11]);
      w1.z = pk2(kA[it][12], kA[it][13]); w1.w = pk2(kA[it][14], kA[it][15]);
      *(u32x4*)((char*)&Kt[0] + swzK(kr, c16)) = w0;
      *(u32x4*)((char*)&Kt[0] + swzK(kr, c16 + 8)) = w1;
    }
#pragma unroll
    for (int it = 0; it < 4; ++it) {
      int k0 = it * 16 + 4 * w + 2 * (lane >> 5);
      int d4 = (lane & 31) * 4;
#pragma unroll
      for (int i = 0; i < 4; ++i)
        *(unsigned*)((char*)&Vt[0] + swzV(d4 + i, k0)) = pk2(vA[it][i], vB[it][i]);
    }
  };

  LOAD(0);

  for (int t = 0; t < nt; ++t) {
    const int kbase = t * 64;
    WRITE();
    __syncthreads();
    if (t + 1 < nt) LOAD(t + 1);   // prefetch next tile; latency hides under compute

    // ---- S = Q K^T (D-layout: col=lane&15, row=(lane>>4)*4+reg) ----
    f32x4 s[2][4];
#pragma unroll
    for (int rs = 0; rs < 2; ++rs)
#pragma unroll
      for (int cb = 0; cb < 4; ++cb) s[rs][cb] = f32x4{0.f, 0.f, 0.f, 0.f};
    __builtin_amdgcn_s_setprio(1);
#pragma unroll
    for (int cb = 0; cb < 4; ++cb)
#pragma unroll
      for (int c = 0; c < 4; ++c) {
        bf16x8 bk = *(const bf16x8*)((char*)&Kt[0] + swzK(16 * cb + r, 32 * c + 8 * g));
        s[0][cb] = mfma16(aQ[0][c], bk, s[0][cb]);
        s[1][cb] = mfma16(aQ[1][c], bk, s[1][cb]);
      }
    __builtin_amdgcn_s_setprio(0);

    // ---- mask + online softmax + P -> LDS ----
#pragma unroll
    for (int rs = 0; rs < 2; ++rs) {
      f32x4 ps[4];
#pragma unroll
      for (int cb = 0; cb < 4; ++cb) {
        bool valid = (kbase + 16 * cb + r) < vlen;
#pragma unroll
        for (int q = 0; q < 4; ++q)
          ps[cb][q] = valid ? s[rs][cb][q] * SCALE : NEGV;
      }
      f32x4 rm = ps[0];
#pragma unroll
      for (int cb = 1; cb < 4; ++cb)
#pragma unroll
        for (int q = 0; q < 4; ++q) rm[q] = fmaxf(rm[q], ps[cb][q]);
#pragma unroll
      for (int q = 0; q < 4; ++q) {
        float v = rm[q];
        v = fmaxf(v, __shfl_xor(v, 1));
        v = fmaxf(v, __shfl_xor(v, 2));
        v = fmaxf(v, __shfl_xor(v, 4));
        v = fmaxf(v, __shfl_xor(v, 8));
        rm[q] = v;
      }
      f32x4 mnew, alpha, rsum;
#pragma unroll
      for (int q = 0; q < 4; ++q) {
        mnew[q] = fmaxf(m_[rs][q], rm[q]);
        alpha[q] = __expf(m_[rs][q] - mnew[q]);
        rsum[q] = 0.f;
      }
      f32x4 pw[4];
#pragma unroll
      for (int cb = 0; cb < 4; ++cb)
#pragma unroll
        for (int q = 0; q < 4; ++q) {
          float pv = __expf(ps[cb][q] - mnew[q]);
          pw[cb][q] = pv;
          rsum[q] += pv;
        }
#pragma unroll
      for (int q = 0; q < 4; ++q) {
        float v = rsum[q];
        v += __shfl_xor(v, 1);
        v += __shfl_xor(v, 2);
        v += __shfl_xor(v, 4);
        v += __shfl_xor(v, 8);
        rsum[q] = v;
      }
#pragma unroll
      for (int q = 0; q < 4; ++q) l_[rs][q] = l_[rs][q] * alpha[q] + rsum[q];
      m_[rs] = mnew;
#pragma unroll
      for (int nb = 0; nb < 8; ++nb)
#pragma unroll
        for (int q = 0; q < 4; ++q) o_[rs][nb][q] *= alpha[q];
#pragma unroll
      for (int cb = 0; cb < 4; ++cb)
#pragma unroll
        for (int q = 0; q < 4; ++q)
          *(unsigned short*)((char*)&Pt[w][0] + swzP(rs * 16 + 4 * g + q, 16 * cb + r)) =
              f2b(pw[cb][q]);
    }

    // ---- O += P @ V ----
    bf16x8 ap[2][2];
#pragma unroll
    for (int rs = 0; rs < 2; ++rs)
#pragma unroll
      for (int c2 = 0; c2 < 2; ++c2)
        ap[rs][c2] = *(const bf16x8*)((char*)&Pt[w][0] + swzP(rs * 16 + r, 32 * c2 + 8 * g));
    __builtin_amdgcn_s_setprio(1);
#pragma unroll
    for (int nb = 0; nb < 8; ++nb)
#pragma unroll
      for (int c2 = 0; c2 < 2; ++c2) {
        bf16x8 bv = *(const bf16x8*)((char*)&Vt[0] + swzV(16 * nb + r, 32 * c2 + 8 * g));
        o_[0][nb] = mfma16(ap[0][c2], bv, o_[0][nb]);
        o_[1][nb] = mfma16(ap[1][c2], bv, o_[1][nb]);
      }
    __builtin_amdgcn_s_setprio(0);
    __syncthreads();
  }

  // ---- epilogue: normalize and store ----
#pragma unroll
  for (int rs = 0; rs < 2; ++rs) {
    f32x4 rcp;
#pragma unroll
    for (int q = 0; q < 4; ++q) rcp[q] = 1.f / l_[rs][q];
#pragma unroll
    for (int nb = 0; nb < 8; ++nb)
#pragma unroll
      for (int q = 0; q < 4; ++q) {
        int row = qbase + w * 32 + rs * 16 + 4 * g + q;
        out[base + (size_t)row * DD + 16 * nb + r] = o_[rs][nb][q] * rcp[q];
      }
  }
}

// ---------------- out += q_mult @ M / (fro + eps)  -------------------------
__global__ void k_multadd(const float* __restrict__ qm, const float* __restrict__ M,
                          const float* __restrict__ fro, float* __restrict__ out) {
  int bh = blockIdx.y, b = bh >> 4;
  int l = blockIdx.x * 128 + (threadIdx.x & 127);
  int dh = (threadIdx.x >> 7) * 64;
  float inv = 1.0f / (fro[b] + 1e-5f);
  const float* qrow = qm + ((size_t)b * LL + l) * DD;
  const float* Mb = M + (size_t)bh * DD * DD + dh;
  float acc[64];
#pragma unroll
  for (int i = 0; i < 64; ++i) acc[i] = 0.f;
  for (int k = 0; k < 128; ++k) {
    float qv = qrow[k];
    const float4* m4 = (const float4*)(Mb + (size_t)k * DD);
#pragma unroll
    for (int i = 0; i < 16; ++i) {
      float4 mm = m4[i];
      acc[4 * i + 0] += qv * mm.x;
      acc[4 * i + 1] += qv * mm.y;
      acc[4 * i + 2] += qv * mm.z;
      acc[4 * i + 3] += qv * mm.w;
    }
  }
  float* op = out + ((size_t)bh * LL + l) * DD + dh;
#pragma unroll
  for (int i = 0; i < 16; ++i) {
    float4 ov = ((float4*)op)[i];
    ov.x += acc[4 * i + 0] * inv;
    ov.y += acc[4 * i + 1] * inv;
    ov.z += acc[4 * i + 2] * inv;
    ov.w += acc[4 * i + 3] * inv;
    ((float4*)op)[i] = ov;
  }
}

// ---------------------------------------------------------------------------
extern "C" void kernel_launch(void* const* d_in, const int* in_sizes, int n_in,
                              void* d_out, int out_size, void* d_ws, size_t ws_size,
                              hipStream_t stream) {
  (void)in_sizes; (void)n_in; (void)out_size; (void)ws_size;
  const float* Q  = (const float*)d_in[0];
  const float* K  = (const float*)d_in[1];
  const float* V  = (const float*)d_in[2];
  const float* qm = (const float*)d_in[3];
  const float* km = (const float*)d_in[4];
  const int* vl   = (const int*)d_in[5];
  float* out = (float*)d_out;

  char* ws = (char*)d_ws;
  const size_t off_M  = 0;                  // 32*128*128*4 = 2,097,152
  const size_t off_Gq = 2097152;            // 2*128*128*4  =   131,072
  const size_t off_Gk = off_Gq + 131072;
  const size_t off_fro = off_Gk + 131072;   // 8B (+pad)
  const size_t off_end = off_fro + 256;

  float* Mw  = (float*)(ws + off_M);
  float* Gq  = (float*)(ws + off_Gq);
  float* Gk  = (float*)(ws + off_Gk);
  float* fro = (float*)(ws + off_fro);

  hipMemsetAsync(d_ws, 0, off_end, stream);

  k_flash<<<dim3(32, 16), 256, 0, stream>>>(Q, K, V, vl, out);
  k_gram<<<dim3(16, 4, 4), 128, 0, stream>>>(qm, km, Gq, Gk);
  k_fro<<<2, 256, 0, stream>>>(Gq, Gk, fro);
  k_M<<<dim3(32, 16), 256, 0, stream>>>(km, V, Mw);
  k_multadd<<<dim3(16, 32), 256, 0, stream>>>(qm, Mw, fro, out);
}

// Round 3
// 340.291 us; speedup vs baseline: 3.1950x; 2.4939x over previous
//
#include <hip/hip_runtime.h>

// ---------------------------------------------------------------------------
// DotProductAttention: out = softmax(mask(Q K^T * scale)) @ V
//                          + (q_mult @ (kv_mult^T @ V)) / (||q_mult kv_mult^T||_F + eps)
// B=2 H=16 BH=32 L=2048 D=128, f32 in/out, bf16 MFMA internally.
// v3: swapped-QK^T 32x32 MFMA flash (in-register softmax), prep kernels bake
//     bf16 + swizzle into global, flash stages via global_load_lds.
// ---------------------------------------------------------------------------

typedef __attribute__((ext_vector_type(8))) __bf16 bf16x8;
typedef __attribute__((ext_vector_type(16))) float f32x16;
typedef __attribute__((ext_vector_type(4))) unsigned int u32x4;

#define DEV static __device__ __forceinline__

constexpr int LL = 2048, DD = 128, BH = 32;
constexpr float SCALE = 0.08838834764831845f;  // 1/sqrt(128)
constexpr float NEGV = -1e6f;

DEV unsigned pkb(float a, float b) {  // pack two f32 -> bf16x2 (RNE via HW cvt)
  union { __bf16 h[2]; unsigned u; } x;
  x.h[0] = (__bf16)a; x.h[1] = (__bf16)b;
  return x.u;
}
DEV f32x16 mfma32(bf16x8 a, bf16x8 b, f32x16 c) {
  return __builtin_amdgcn_mfma_f32_32x32x16_bf16(a, b, c, 0, 0, 0);
}
DEV void gl16(const void* g, void* l) {
  __builtin_amdgcn_global_load_lds(
      (const __attribute__((address_space(1))) unsigned int*)g,
      (__attribute__((address_space(3))) unsigned int*)l, 16, 0, 0);
}

// ---------------- prep: K -> bf16, per-64-row tile, swizzle baked ----------
// tile (bh, kt) is 16KB; byte(kk,d) = kk*256 + ((d*2) ^ ((kk&15)<<4))
__global__ void prep_K(const float* __restrict__ K, char* __restrict__ Kb) {
#pragma unroll
  for (int i = 0; i < 4; ++i) {
    int cid = i * 262144 + blockIdx.x * 256 + threadIdx.x;  // 1,048,576 chunks
    int h = cid >> 15, k = (cid >> 4) & 2047, c = cid & 15;
    const float* p = K + ((size_t)h * LL + k) * DD + c * 8;
    float4 x0 = *(const float4*)p, x1 = *(const float4*)(p + 4);
    u32x4 v;
    v.x = pkb(x0.x, x0.y); v.y = pkb(x0.z, x0.w);
    v.z = pkb(x1.x, x1.y); v.w = pkb(x1.z, x1.w);
    int kk = k & 63;
    char* dst = Kb + (((size_t)h * 32 + (k >> 6)) << 14) + (kk << 8) +
                ((c ^ (kk & 15)) << 4);
    *(u32x4*)dst = v;
  }
}

// ---------------- prep: V -> bf16 transposed [d][k], swizzle baked ---------
// tile (bh, kt) is 16KB; byte(d,kk) = d*128 + ((kk*2) ^ ((d&7)<<4))
__global__ void prep_V(const float* __restrict__ V, char* __restrict__ Vt) {
  __shared__ float sV[64][128];
  int h = blockIdx.x >> 5, kt = blockIdx.x & 31;
  int tid = threadIdx.x;
  const float* src = V + ((size_t)h * LL + kt * 64) * DD;
#pragma unroll
  for (int i = 0; i < 8; ++i) {
    int idx = i * 256 + tid;  // 2048 float4s
    int row = idx >> 5, c4 = (idx & 31) * 4;
    *(float4*)&sV[row][c4] = *(const float4*)(src + (size_t)row * DD + c4);
  }
  __syncthreads();
  char* dstb = Vt + (((size_t)h * 32 + kt) << 14);
#pragma unroll
  for (int i = 0; i < 4; ++i) {
    int cid = i * 256 + tid;  // 1024 chunks
    int d = cid & 127, kg = cid >> 7;
    u32x4 v;
    v.x = pkb(sV[kg * 8 + 0][d], sV[kg * 8 + 1][d]);
    v.y = pkb(sV[kg * 8 + 2][d], sV[kg * 8 + 3][d]);
    v.z = pkb(sV[kg * 8 + 4][d], sV[kg * 8 + 5][d]);
    v.w = pkb(sV[kg * 8 + 6][d], sV[kg * 8 + 7][d]);
    *(u32x4*)(dstb + (d << 7) + ((kg ^ (d & 7)) << 4)) = v;
  }
}

// ------------------------------ flash attention ----------------------------
// grid (32 bh, 16 qtile), block 256 (4 waves x 32 q-rows), KV tile 64.
// MODE 0: staged from prepped Kb/Vt via global_load_lds (double-buffered).
// MODE 1: fallback, stage from f32 in-kernel (single-buffered).
template <int MODE>
__global__ __launch_bounds__(256, 2)
void k_flash(const char* __restrict__ KbG, const char* __restrict__ VtG,
             const float* __restrict__ Qf, const float* __restrict__ Kf,
             const float* __restrict__ Vf, const int* __restrict__ vl,
             float* __restrict__ out) {
  __shared__ __align__(16) char lds[MODE ? 49152 : 65536];

  const int bh = blockIdx.x, qbase = blockIdx.y * 128;
  const int tid = threadIdx.x, w = tid >> 6, lane = tid & 63;
  const int r32 = lane & 31, hi = lane >> 5;
  const int vlen = vl[bh];
  const size_t base = (size_t)bh * LL * DD;
  const int q = qbase + w * 32 + r32;

  // ---- Q fragments (B-operand, col=lane&31=q, k=hi*8+j), pre-scaled ----
  bf16x8 qfr[8];
#pragma unroll
  for (int ks = 0; ks < 8; ++ks) {
    const float* p = Qf + base + (size_t)q * DD + ks * 16 + hi * 8;
    float4 x0 = *(const float4*)p, x1 = *(const float4*)(p + 4);
    union { unsigned u[4]; bf16x8 v; } u;
    u.u[0] = pkb(x0.x * SCALE, x0.y * SCALE);
    u.u[1] = pkb(x0.z * SCALE, x0.w * SCALE);
    u.u[2] = pkb(x1.x * SCALE, x1.y * SCALE);
    u.u[3] = pkb(x1.z * SCALE, x1.w * SCALE);
    qfr[ks] = u.v;
  }

  f32x16 o[4];
#pragma unroll
  for (int dt = 0; dt < 4; ++dt)
#pragma unroll
    for (int e = 0; e < 16; ++e) o[dt][e] = 0.f;
  float mrun = -3e38f, lrun = 0.f;

  int nt = (vlen == 0) ? 32 : ((vlen + 63) >> 6);

  // ---- per-tile compute: swapped QK^T, in-register softmax, swapped PV ----
  auto compute = [&](const char* Kl, const char* Vl, int kbase) {
    f32x16 s0, s1;
#pragma unroll
    for (int e = 0; e < 16; ++e) { s0[e] = 0.f; s1[e] = 0.f; }
    __builtin_amdgcn_s_setprio(1);
#pragma unroll
    for (int ks = 0; ks < 8; ++ks) {
      int cb = ((2 * ks + hi) ^ (r32 & 15)) << 4;
      bf16x8 a0 = *(const bf16x8*)(Kl + r32 * 256 + cb);
      bf16x8 a1 = *(const bf16x8*)(Kl + 8192 + r32 * 256 + cb);
      s0 = mfma32(a0, qfr[ks], s0);
      s1 = mfma32(a1, qfr[ks], s1);
    }
    __builtin_amdgcn_s_setprio(0);

    // mask (only when tile partially valid; vlen==0 masks everything)
    if (kbase + 64 > vlen) {
#pragma unroll
      for (int e = 0; e < 16; ++e) {
        int k0 = kbase + (e & 3) + 8 * (e >> 2) + 4 * hi;
        if (k0 >= vlen) s0[e] = NEGV;
        if (k0 + 32 >= vlen) s1[e] = NEGV;
      }
    }
    // row max: in-lane tree + pair exchange
    f32x16 mx;
#pragma unroll
    for (int e = 0; e < 16; ++e) mx[e] = fmaxf(s0[e], s1[e]);
#pragma unroll
    for (int st = 8; st; st >>= 1)
#pragma unroll
      for (int e = 0; e < st; ++e) mx[e] = fmaxf(mx[e], mx[e + st]);
    float pm = fmaxf(mx[0], __shfl_xor(mx[0], 32));

    // defer-max (T13, THR=8)
    if (!__all(pm <= mrun + 8.f)) {
      float mn = fmaxf(mrun, pm);
      float al = __expf(mrun - mn);
      lrun *= al;
#pragma unroll
      for (int dt = 0; dt < 4; ++dt)
#pragma unroll
        for (int e = 0; e < 16; ++e) o[dt][e] *= al;
      mrun = mn;
    }
    // exp + in-lane sum (pair halves summed at epilogue)
#pragma unroll
    for (int e = 0; e < 16; ++e) {
      s0[e] = __expf(s0[e] - mrun);
      s1[e] = __expf(s1[e] - mrun);
    }
    f32x16 sm;
#pragma unroll
    for (int e = 0; e < 16; ++e) sm[e] = s0[e] + s1[e];
#pragma unroll
    for (int st = 8; st; st >>= 1)
#pragma unroll
      for (int e = 0; e < st; ++e) sm[e] += sm[e + st];
    lrun += sm[0];

    // pack P -> bf16 B-frags (k local to lane pair; exchange via shfl_xor 32)
    bf16x8 PA[4];
#pragma unroll
    for (int ks = 0; ks < 4; ++ks) {
      const f32x16& sv = (ks < 2) ? s0 : s1;
      int b = (ks & 1) * 8;
      unsigned x1 = pkb(sv[b + 0], sv[b + 1]);
      unsigned x2 = pkb(sv[b + 2], sv[b + 3]);
      unsigned y1 = pkb(sv[b + 4], sv[b + 5]);
      unsigned y2 = pkb(sv[b + 6], sv[b + 7]);
      unsigned sx1 = __shfl_xor(x1, 32), sx2 = __shfl_xor(x2, 32);
      unsigned sy1 = __shfl_xor(y1, 32), sy2 = __shfl_xor(y2, 32);
      union { unsigned u[4]; bf16x8 v; } pu;
      pu.u[0] = hi ? sy1 : x1;
      pu.u[1] = hi ? sy2 : x2;
      pu.u[2] = hi ? y1 : sx1;
      pu.u[3] = hi ? y2 : sx2;
      PA[ks] = pu.v;
    }
    // PV (swapped: O^T tile, lane owns q column)
    __builtin_amdgcn_s_setprio(1);
#pragma unroll
    for (int dt = 0; dt < 4; ++dt)
#pragma unroll
      for (int ks = 0; ks < 4; ++ks) {
        bf16x8 av = *(const bf16x8*)(Vl + (dt * 32 + r32) * 128 +
                                     (((2 * ks + hi) ^ (r32 & 7)) << 4));
        o[dt] = mfma32(av, PA[ks], o[dt]);
      }
    __builtin_amdgcn_s_setprio(0);
  };

  if (MODE == 0) {
    auto stage = [&](int t, int c2) {
      const char* gk = KbG + (((size_t)bh * 32 + t) << 14) + (w << 12) + lane * 16;
      const char* gv = VtG + (((size_t)bh * 32 + t) << 14) + (w << 12) + lane * 16;
      char* lk = lds + c2 * 32768 + (w << 12);
      char* lv = lds + c2 * 32768 + 16384 + (w << 12);
#pragma unroll
      for (int i = 0; i < 4; ++i) {
        gl16(gk + i * 1024, lk + i * 1024);
        gl16(gv + i * 1024, lv + i * 1024);
      }
    };
    stage(0, 0);
    __syncthreads();  // compiler drains vmcnt before barrier
    int cur = 0;
    for (int t = 0; t < nt; ++t) {
      if (t + 1 < nt) stage(t + 1, cur ^ 1);  // prefetch hides under compute
      compute(lds + cur * 32768, lds + cur * 32768 + 16384, t * 64);
      __syncthreads();
      cur ^= 1;
    }
  } else {
    // fallback: stage from f32, single-buffered, in-LDS V transpose
    char* Kl = lds;
    char* Vl = lds + 16384;
    char* Vtmp = lds + 32768;
    for (int t = 0; t < nt; ++t) {
      int kbase = t * 64;
#pragma unroll
      for (int i = 0; i < 4; ++i) {
        int idx = i * 256 + tid;
        int kk = idx >> 4, c = idx & 15;
        const float* p = Kf + base + (size_t)(kbase + kk) * DD + c * 8;
        float4 x0 = *(const float4*)p, x1 = *(const float4*)(p + 4);
        u32x4 v;
        v.x = pkb(x0.x, x0.y); v.y = pkb(x0.z, x0.w);
        v.z = pkb(x1.x, x1.y); v.w = pkb(x1.z, x1.w);
        *(u32x4*)(Kl + (kk << 8) + ((c ^ (kk & 15)) << 4)) = v;
        const float* pv = Vf + base + (size_t)(kbase + kk) * DD + c * 8;
        float4 y0 = *(const float4*)pv, y1 = *(const float4*)(pv + 4);
        u32x4 vw;
        vw.x = pkb(y0.x, y0.y); vw.y = pkb(y0.z, y0.w);
        vw.z = pkb(y1.x, y1.y); vw.w = pkb(y1.z, y1.w);
        *(u32x4*)(Vtmp + (kk << 8) + (c << 4)) = vw;
      }
      __syncthreads();
#pragma unroll
      for (int i = 0; i < 4; ++i) {
        int cid = i * 256 + tid;
        int d = cid & 127, kg = cid >> 7;
        unsigned short t0[8];
#pragma unroll
        for (int j = 0; j < 8; ++j)
          t0[j] = *(const unsigned short*)(Vtmp + ((kg * 8 + j) << 8) + d * 2);
        u32x4 v;
        v.x = (unsigned)t0[0] | ((unsigned)t0[1] << 16);
        v.y = (unsigned)t0[2] | ((unsigned)t0[3] << 16);
        v.z = (unsigned)t0[4] | ((unsigned)t0[5] << 16);
        v.w = (unsigned)t0[6] | ((unsigned)t0[7] << 16);
        *(u32x4*)(Vl + (d << 7) + ((kg ^ (d & 7)) << 4)) = v;
      }
      __syncthreads();
      compute(Kl, Vl, kbase);
      __syncthreads();
    }
  }

  // ---- epilogue: combine pair l, normalize, store (lane owns q-row) ----
  float lt = lrun + __shfl_xor(lrun, 32);
  float inv = 1.f / lt;
  float* op = out + base + (size_t)q * DD;
#pragma unroll
  for (int dt = 0; dt < 4; ++dt)
#pragma unroll
    for (int rq = 0; rq < 4; ++rq) {
      float4 v;
      v.x = o[dt][4 * rq + 0] * inv;
      v.y = o[dt][4 * rq + 1] * inv;
      v.z = o[dt][4 * rq + 2] * inv;
      v.w = o[dt][4 * rq + 3] * inv;
      *(float4*)(op + dt * 32 + rq * 8 + hi * 4) = v;
    }
}

// ------------------- Gram matrices: G = A^T A per batch --------------------
__global__ void k_gram(const float* __restrict__ qm, const float* __restrict__ km,
                       float* __restrict__ Gq, float* __restrict__ Gk) {
  int which = blockIdx.z >> 1, b = blockIdx.z & 1;
  const float* A = (which ? km : qm) + (size_t)b * LL * DD;
  float* G = (which ? Gk : Gq) + (size_t)b * DD * DD;
  int i0 = blockIdx.x * 8;
  int l0 = blockIdx.y * 512;
  __shared__ float s[32][128];
  float acc[8];
#pragma unroll
  for (int i = 0; i < 8; ++i) acc[i] = 0.f;
  for (int ch = 0; ch < 16; ++ch) {
    __syncthreads();
    for (int rr = 0; rr < 32; ++rr)
      s[rr][threadIdx.x] = A[(size_t)(l0 + ch * 32 + rr) * DD + threadIdx.x];
    __syncthreads();
    for (int ll = 0; ll < 32; ++ll) {
      float aj = s[ll][threadIdx.x];
#pragma unroll
      for (int ii = 0; ii < 8; ++ii) acc[ii] += s[ll][i0 + ii] * aj;
    }
  }
#pragma unroll
  for (int ii = 0; ii < 8; ++ii)
    atomicAdd(&G[(size_t)(i0 + ii) * DD + threadIdx.x], acc[ii]);
}

// ------------------- fro[b] = sqrt(sum Gq .* Gk) ---------------------------
__global__ void k_fro(const float* __restrict__ Gq, const float* __restrict__ Gk,
                      float* __restrict__ fro) {
  int b = blockIdx.x;
  const float* gq = Gq + (size_t)b * DD * DD;
  const float* gk = Gk + (size_t)b * DD * DD;
  float acc = 0.f;
  for (int i = threadIdx.x; i < DD * DD; i += 256) acc += gq[i] * gk[i];
#pragma unroll
  for (int m = 32; m; m >>= 1) acc += __shfl_xor(acc, m);
  __shared__ float sbuf[4];
  if ((threadIdx.x & 63) == 0) sbuf[threadIdx.x >> 6] = acc;
  __syncthreads();
  if (threadIdx.x == 0) fro[b] = sqrtf(sbuf[0] + sbuf[1] + sbuf[2] + sbuf[3]);
}

// ------------------- M[bh] = kv_mult[b]^T @ V[bh]  (128x128, f32) ----------
__global__ void k_M(const float* __restrict__ km, const float* __restrict__ Vf,
                    float* __restrict__ M) {
  int bh = blockIdx.x, b = bh >> 4;
  int l0 = blockIdx.y * 128;
  __shared__ float skv[16][128];
  __shared__ float sv[16][128];
  int j0 = (threadIdx.x & 31) * 4;
  int i0 = (threadIdx.x >> 5) * 16;
  float acc[16][4];
#pragma unroll
  for (int i = 0; i < 16; ++i)
#pragma unroll
    for (int qq = 0; qq < 4; ++qq) acc[i][qq] = 0.f;
  for (int c = 0; c < 8; ++c) {
    __syncthreads();
    for (int x = 0; x < 8; ++x) {
      int idx = x * 256 + threadIdx.x;
      int rr = idx >> 7, cc = idx & 127;
      skv[rr][cc] = km[(size_t)(b * LL + l0 + c * 16 + rr) * DD + cc];
      sv[rr][cc] = Vf[(size_t)(bh * LL + l0 + c * 16 + rr) * DD + cc];
    }
    __syncthreads();
    for (int ll = 0; ll < 16; ++ll) {
      float a0 = sv[ll][j0], a1 = sv[ll][j0 + 1];
      float a2 = sv[ll][j0 + 2], a3 = sv[ll][j0 + 3];
#pragma unroll
      for (int ii = 0; ii < 16; ++ii) {
        float kv = skv[ll][i0 + ii];
        acc[ii][0] += kv * a0;
        acc[ii][1] += kv * a1;
        acc[ii][2] += kv * a2;
        acc[ii][3] += kv * a3;
      }
    }
  }
#pragma unroll
  for (int ii = 0; ii < 16; ++ii)
#pragma unroll
    for (int qq = 0; qq < 4; ++qq)
      atomicAdd(&M[(size_t)bh * DD * DD + (size_t)(i0 + ii) * DD + j0 + qq],
                acc[ii][qq]);
}

// ---------------- out += q_mult @ M / (fro + eps)  -------------------------
__global__ void k_multadd(const float* __restrict__ qm, const float* __restrict__ M,
                          const float* __restrict__ fro, float* __restrict__ out) {
  int bh = blockIdx.y, b = bh >> 4;
  int l0 = blockIdx.x * 128;
  int row = threadIdx.x & 127, half = threadIdx.x >> 7, dh = half * 64;
  __shared__ float sq[16][129];
  __shared__ float sM[16][128];
  float inv = 1.f / (fro[b] + 1e-5f);
  float acc[64];
#pragma unroll
  for (int i = 0; i < 64; ++i) acc[i] = 0.f;
  for (int c = 0; c < 8; ++c) {
    __syncthreads();
#pragma unroll
    for (int i = 0; i < 2; ++i) {
      int id2 = i * 256 + threadIdx.x;  // 512 iters
      int rr = id2 >> 2, k4 = (id2 & 3) * 4;
      float4 x = *(const float4*)(qm + ((size_t)b * LL + l0 + rr) * DD + c * 16 + k4);
      sq[k4 + 0][rr] = x.x; sq[k4 + 1][rr] = x.y;
      sq[k4 + 2][rr] = x.z; sq[k4 + 3][rr] = x.w;
      int rr2 = id2 >> 5, d4 = (id2 & 31) * 4;
      *(float4*)&sM[rr2][d4] =
          *(const float4*)(M + (size_t)bh * 16384 + (size_t)(c * 16 + rr2) * DD + d4);
    }
    __syncthreads();
#pragma unroll
    for (int kk = 0; kk < 16; ++kk) {
      float qv = sq[kk][row];
      const float4* m4 = (const float4*)&sM[kk][dh];
#pragma unroll
      for (int i = 0; i < 16; ++i) {
        float4 mm = m4[i];
        acc[4 * i + 0] += qv * mm.x;
        acc[4 * i + 1] += qv * mm.y;
        acc[4 * i + 2] += qv * mm.z;
        acc[4 * i + 3] += qv * mm.w;
      }
    }
  }
  float* op = out + ((size_t)bh * LL + l0 + row) * DD + dh;
#pragma unroll
  for (int i = 0; i < 16; ++i) {
    float4 ov = ((float4*)op)[i];
    ov.x += acc[4 * i + 0] * inv;
    ov.y += acc[4 * i + 1] * inv;
    ov.z += acc[4 * i + 2] * inv;
    ov.w += acc[4 * i + 3] * inv;
    ((float4*)op)[i] = ov;
  }
}

// ---------------------------------------------------------------------------
extern "C" void kernel_launch(void* const* d_in, const int* in_sizes, int n_in,
                              void* d_out, int out_size, void* d_ws, size_t ws_size,
                              hipStream_t stream) {
  (void)in_sizes; (void)n_in; (void)out_size;
  const float* Q = (const float*)d_in[0];
  const float* K = (const float*)d_in[1];
  const float* V = (const float*)d_in[2];
  const float* qm = (const float*)d_in[3];
  const float* km = (const float*)d_in[4];
  const int* vl = (const int*)d_in[5];
  float* out = (float*)d_out;

  char* ws = (char*)d_ws;
  const size_t off_M = 0;                      // 32*128*128*4 = 2 MB
  const size_t off_Gq = 2097152;
  const size_t off_Gk = off_Gq + 131072;
  const size_t off_fro = off_Gk + 131072;
  const size_t off_Kb = off_fro + 256;         // 16 MB bf16 K (swizzled tiles)
  const size_t szb = (size_t)BH * LL * DD * 2;
  const size_t off_Vt = off_Kb + szb;          // 16 MB bf16 V^T (swizzled tiles)
  const size_t off_end = off_Vt + szb;
  bool fits = ws_size >= off_end;

  float* Mw = (float*)(ws + off_M);
  float* Gq = (float*)(ws + off_Gq);
  float* Gk = (float*)(ws + off_Gk);
  float* fro = (float*)(ws + off_fro);

  hipMemsetAsync(d_ws, 0, off_Kb, stream);

  if (fits) {
    prep_K<<<1024, 256, 0, stream>>>(K, ws + off_Kb);
    prep_V<<<1024, 256, 0, stream>>>(V, ws + off_Vt);
    k_flash<0><<<dim3(32, 16), 256, 0, stream>>>(ws + off_Kb, ws + off_Vt,
                                                 Q, K, V, vl, out);
  } else {
    k_flash<1><<<dim3(32, 16), 256, 0, stream>>>(nullptr, nullptr,
                                                 Q, K, V, vl, out);
  }
  k_gram<<<dim3(16, 4, 4), 128, 0, stream>>>(qm, km, Gq, Gk);
  k_fro<<<2, 256, 0, stream>>>(Gq, Gk, fro);
  k_M<<<dim3(32, 16), 256, 0, stream>>>(km, V, Mw);
  k_multadd<<<dim3(16, 32), 256, 0, stream>>>(qm, Mw, fro, out);
}

// Round 4
// 236.641 us; speedup vs baseline: 4.5944x; 1.4380x over previous
//
#include <hip/hip_runtime.h>

// ---------------------------------------------------------------------------
// DotProductAttention: out = softmax(mask(Q K^T * scale)) @ V
//                          + (q_mult @ (kv_mult^T @ V)) / (||q_mult kv_mult^T||_F + eps)
// B=2 H=16 BH=32 L=2048 D=128, f32 in/out, bf16 MFMA internally.
// v4: k_M atomics -> split-K partials + reduce (reuses Kb region); fused prep.
// ---------------------------------------------------------------------------

typedef __attribute__((ext_vector_type(8))) __bf16 bf16x8;
typedef __attribute__((ext_vector_type(16))) float f32x16;
typedef __attribute__((ext_vector_type(4))) unsigned int u32x4;

#define DEV static __device__ __forceinline__

constexpr int LL = 2048, DD = 128, BH = 32;
constexpr float SCALE = 0.08838834764831845f;  // 1/sqrt(128)
constexpr float NEGV = -1e6f;

DEV unsigned pkb(float a, float b) {  // pack two f32 -> bf16x2 (RNE via HW cvt)
  union { __bf16 h[2]; unsigned u; } x;
  x.h[0] = (__bf16)a; x.h[1] = (__bf16)b;
  return x.u;
}
DEV f32x16 mfma32(bf16x8 a, bf16x8 b, f32x16 c) {
  return __builtin_amdgcn_mfma_f32_32x32x16_bf16(a, b, c, 0, 0, 0);
}
DEV void gl16(const void* g, void* l) {
  __builtin_amdgcn_global_load_lds(
      (const __attribute__((address_space(1))) unsigned int*)g,
      (__attribute__((address_space(3))) unsigned int*)l, 16, 0, 0);
}

// -------- fused prep: K -> bf16 swizzled tiles; V -> bf16 [d][k] tiles -----
// K tile (bh,kt) 16KB; byte(kk,d) = kk*256 + ((d*2) ^ ((kk&15)<<4))
// V tile (bh,kt) 16KB; byte(d,kk) = d*128 + ((kk*2) ^ ((d&7)<<4))
__global__ void prep_KV(const float* __restrict__ K, const float* __restrict__ V,
                        char* __restrict__ Kb, char* __restrict__ Vt) {
  if (blockIdx.x < 1024) {
#pragma unroll
    for (int i = 0; i < 4; ++i) {
      int cid = i * 262144 + blockIdx.x * 256 + threadIdx.x;  // 1,048,576 chunks
      int h = cid >> 15, k = (cid >> 4) & 2047, c = cid & 15;
      const float* p = K + ((size_t)h * LL + k) * DD + c * 8;
      float4 x0 = *(const float4*)p, x1 = *(const float4*)(p + 4);
      u32x4 v;
      v.x = pkb(x0.x, x0.y); v.y = pkb(x0.z, x0.w);
      v.z = pkb(x1.x, x1.y); v.w = pkb(x1.z, x1.w);
      int kk = k & 63;
      char* dst = Kb + (((size_t)h * 32 + (k >> 6)) << 14) + (kk << 8) +
                  ((c ^ (kk & 15)) << 4);
      *(u32x4*)dst = v;
    }
  } else {
    __shared__ float sV[64][128];
    int bid = blockIdx.x - 1024;
    int h = bid >> 5, kt = bid & 31;
    int tid = threadIdx.x;
    const float* src = V + ((size_t)h * LL + kt * 64) * DD;
#pragma unroll
    for (int i = 0; i < 8; ++i) {
      int idx = i * 256 + tid;  // 2048 float4s
      int row = idx >> 5, c4 = (idx & 31) * 4;
      *(float4*)&sV[row][c4] = *(const float4*)(src + (size_t)row * DD + c4);
    }
    __syncthreads();
    char* dstb = Vt + (((size_t)h * 32 + kt) << 14);
#pragma unroll
    for (int i = 0; i < 4; ++i) {
      int cid = i * 256 + tid;  // 1024 chunks
      int d = cid & 127, kg = cid >> 7;
      u32x4 v;
      v.x = pkb(sV[kg * 8 + 0][d], sV[kg * 8 + 1][d]);
      v.y = pkb(sV[kg * 8 + 2][d], sV[kg * 8 + 3][d]);
      v.z = pkb(sV[kg * 8 + 4][d], sV[kg * 8 + 5][d]);
      v.w = pkb(sV[kg * 8 + 6][d], sV[kg * 8 + 7][d]);
      *(u32x4*)(dstb + (d << 7) + ((kg ^ (d & 7)) << 4)) = v;
    }
  }
}

// ------------------------------ flash attention ----------------------------
// grid (32 bh, 16 qtile), block 256 (4 waves x 32 q-rows), KV tile 64.
template <int MODE>
__global__ __launch_bounds__(256, 2)
void k_flash(const char* __restrict__ KbG, const char* __restrict__ VtG,
             const float* __restrict__ Qf, const float* __restrict__ Kf,
             const float* __restrict__ Vf, const int* __restrict__ vl,
             float* __restrict__ out) {
  __shared__ __align__(16) char lds[MODE ? 49152 : 65536];

  const int bh = blockIdx.x, qbase = blockIdx.y * 128;
  const int tid = threadIdx.x, w = tid >> 6, lane = tid & 63;
  const int r32 = lane & 31, hi = lane >> 5;
  const int vlen = vl[bh];
  const size_t base = (size_t)bh * LL * DD;
  const int q = qbase + w * 32 + r32;

  // ---- Q fragments (B-operand, col=lane&31=q, k=hi*8+j), pre-scaled ----
  bf16x8 qfr[8];
#pragma unroll
  for (int ks = 0; ks < 8; ++ks) {
    const float* p = Qf + base + (size_t)q * DD + ks * 16 + hi * 8;
    float4 x0 = *(const float4*)p, x1 = *(const float4*)(p + 4);
    union { unsigned u[4]; bf16x8 v; } u;
    u.u[0] = pkb(x0.x * SCALE, x0.y * SCALE);
    u.u[1] = pkb(x0.z * SCALE, x0.w * SCALE);
    u.u[2] = pkb(x1.x * SCALE, x1.y * SCALE);
    u.u[3] = pkb(x1.z * SCALE, x1.w * SCALE);
    qfr[ks] = u.v;
  }

  f32x16 o[4];
#pragma unroll
  for (int dt = 0; dt < 4; ++dt)
#pragma unroll
    for (int e = 0; e < 16; ++e) o[dt][e] = 0.f;
  float mrun = -3e38f, lrun = 0.f;

  int nt = (vlen == 0) ? 32 : ((vlen + 63) >> 6);

  auto compute = [&](const char* Kl, const char* Vl, int kbase) {
    f32x16 s0, s1;
#pragma unroll
    for (int e = 0; e < 16; ++e) { s0[e] = 0.f; s1[e] = 0.f; }
    __builtin_amdgcn_s_setprio(1);
#pragma unroll
    for (int ks = 0; ks < 8; ++ks) {
      int cb = ((2 * ks + hi) ^ (r32 & 15)) << 4;
      bf16x8 a0 = *(const bf16x8*)(Kl + r32 * 256 + cb);
      bf16x8 a1 = *(const bf16x8*)(Kl + 8192 + r32 * 256 + cb);
      s0 = mfma32(a0, qfr[ks], s0);
      s1 = mfma32(a1, qfr[ks], s1);
    }
    __builtin_amdgcn_s_setprio(0);

    if (kbase + 64 > vlen) {
#pragma unroll
      for (int e = 0; e < 16; ++e) {
        int k0 = kbase + (e & 3) + 8 * (e >> 2) + 4 * hi;
        if (k0 >= vlen) s0[e] = NEGV;
        if (k0 + 32 >= vlen) s1[e] = NEGV;
      }
    }
    f32x16 mx;
#pragma unroll
    for (int e = 0; e < 16; ++e) mx[e] = fmaxf(s0[e], s1[e]);
#pragma unroll
    for (int st = 8; st; st >>= 1)
#pragma unroll
      for (int e = 0; e < st; ++e) mx[e] = fmaxf(mx[e], mx[e + st]);
    float pm = fmaxf(mx[0], __shfl_xor(mx[0], 32));

    if (!__all(pm <= mrun + 8.f)) {  // defer-max (T13)
      float mn = fmaxf(mrun, pm);
      float al = __expf(mrun - mn);
      lrun *= al;
#pragma unroll
      for (int dt = 0; dt < 4; ++dt)
#pragma unroll
        for (int e = 0; e < 16; ++e) o[dt][e] *= al;
      mrun = mn;
    }
#pragma unroll
    for (int e = 0; e < 16; ++e) {
      s0[e] = __expf(s0[e] - mrun);
      s1[e] = __expf(s1[e] - mrun);
    }
    f32x16 sm;
#pragma unroll
    for (int e = 0; e < 16; ++e) sm[e] = s0[e] + s1[e];
#pragma unroll
    for (int st = 8; st; st >>= 1)
#pragma unroll
      for (int e = 0; e < st; ++e) sm[e] += sm[e + st];
    lrun += sm[0];

    bf16x8 PA[4];
#pragma unroll
    for (int ks = 0; ks < 4; ++ks) {
      const f32x16& sv = (ks < 2) ? s0 : s1;
      int b = (ks & 1) * 8;
      unsigned x1 = pkb(sv[b + 0], sv[b + 1]);
      unsigned x2 = pkb(sv[b + 2], sv[b + 3]);
      unsigned y1 = pkb(sv[b + 4], sv[b + 5]);
      unsigned y2 = pkb(sv[b + 6], sv[b + 7]);
      unsigned sx1 = __shfl_xor(x1, 32), sx2 = __shfl_xor(x2, 32);
      unsigned sy1 = __shfl_xor(y1, 32), sy2 = __shfl_xor(y2, 32);
      union { unsigned u[4]; bf16x8 v; } pu;
      pu.u[0] = hi ? sy1 : x1;
      pu.u[1] = hi ? sy2 : x2;
      pu.u[2] = hi ? y1 : sx1;
      pu.u[3] = hi ? y2 : sx2;
      PA[ks] = pu.v;
    }
    __builtin_amdgcn_s_setprio(1);
#pragma unroll
    for (int dt = 0; dt < 4; ++dt)
#pragma unroll
      for (int ks = 0; ks < 4; ++ks) {
        bf16x8 av = *(const bf16x8*)(Vl + (dt * 32 + r32) * 128 +
                                     (((2 * ks + hi) ^ (r32 & 7)) << 4));
        o[dt] = mfma32(av, PA[ks], o[dt]);
      }
    __builtin_amdgcn_s_setprio(0);
  };

  if (MODE == 0) {
    auto stage = [&](int t, int c2) {
      const char* gk = KbG + (((size_t)bh * 32 + t) << 14) + (w << 12) + lane * 16;
      const char* gv = VtG + (((size_t)bh * 32 + t) << 14) + (w << 12) + lane * 16;
      char* lk = lds + c2 * 32768 + (w << 12);
      char* lv = lds + c2 * 32768 + 16384 + (w << 12);
#pragma unroll
      for (int i = 0; i < 4; ++i) {
        gl16(gk + i * 1024, lk + i * 1024);
        gl16(gv + i * 1024, lv + i * 1024);
      }
    };
    stage(0, 0);
    __syncthreads();
    int cur = 0;
    for (int t = 0; t < nt; ++t) {
      if (t + 1 < nt) stage(t + 1, cur ^ 1);
      compute(lds + cur * 32768, lds + cur * 32768 + 16384, t * 64);
      __syncthreads();
      cur ^= 1;
    }
  } else {
    char* Kl = lds;
    char* Vl = lds + 16384;
    char* Vtmp = lds + 32768;
    for (int t = 0; t < nt; ++t) {
      int kbase = t * 64;
#pragma unroll
      for (int i = 0; i < 4; ++i) {
        int idx = i * 256 + tid;
        int kk = idx >> 4, c = idx & 15;
        const float* p = Kf + base + (size_t)(kbase + kk) * DD + c * 8;
        float4 x0 = *(const float4*)p, x1 = *(const float4*)(p + 4);
        u32x4 v;
        v.x = pkb(x0.x, x0.y); v.y = pkb(x0.z, x0.w);
        v.z = pkb(x1.x, x1.y); v.w = pkb(x1.z, x1.w);
        *(u32x4*)(Kl + (kk << 8) + ((c ^ (kk & 15)) << 4)) = v;
        const float* pv = Vf + base + (size_t)(kbase + kk) * DD + c * 8;
        float4 y0 = *(const float4*)pv, y1 = *(const float4*)(pv + 4);
        u32x4 vw;
        vw.x = pkb(y0.x, y0.y); vw.y = pkb(y0.z, y0.w);
        vw.z = pkb(y1.x, y1.y); vw.w = pkb(y1.z, y1.w);
        *(u32x4*)(Vtmp + (kk << 8) + (c << 4)) = vw;
      }
      __syncthreads();
#pragma unroll
      for (int i = 0; i < 4; ++i) {
        int cid = i * 256 + tid;
        int d = cid & 127, kg = cid >> 7;
        unsigned short t0[8];
#pragma unroll
        for (int j = 0; j < 8; ++j)
          t0[j] = *(const unsigned short*)(Vtmp + ((kg * 8 + j) << 8) + d * 2);
        u32x4 v;
        v.x = (unsigned)t0[0] | ((unsigned)t0[1] << 16);
        v.y = (unsigned)t0[2] | ((unsigned)t0[3] << 16);
        v.z = (unsigned)t0[4] | ((unsigned)t0[5] << 16);
        v.w = (unsigned)t0[6] | ((unsigned)t0[7] << 16);
        *(u32x4*)(Vl + (d << 7) + ((kg ^ (d & 7)) << 4)) = v;
      }
      __syncthreads();
      compute(Kl, Vl, kbase);
      __syncthreads();
    }
  }

  float lt = lrun + __shfl_xor(lrun, 32);
  float inv = 1.f / lt;
  float* op = out + base + (size_t)q * DD;
#pragma unroll
  for (int dt = 0; dt < 4; ++dt)
#pragma unroll
    for (int rq = 0; rq < 4; ++rq) {
      float4 v;
      v.x = o[dt][4 * rq + 0] * inv;
      v.y = o[dt][4 * rq + 1] * inv;
      v.z = o[dt][4 * rq + 2] * inv;
      v.w = o[dt][4 * rq + 3] * inv;
      *(float4*)(op + dt * 32 + rq * 8 + hi * 4) = v;
    }
}

// ------------------- Gram matrices: G = A^T A per batch --------------------
__global__ void k_gram(const float* __restrict__ qm, const float* __restrict__ km,
                       float* __restrict__ Gq, float* __restrict__ Gk) {
  int which = blockIdx.z >> 1, b = blockIdx.z & 1;
  const float* A = (which ? km : qm) + (size_t)b * LL * DD;
  float* G = (which ? Gk : Gq) + (size_t)b * DD * DD;
  int i0 = blockIdx.x * 8;
  int l0 = blockIdx.y * 512;
  __shared__ float s[32][128];
  float acc[8];
#pragma unroll
  for (int i = 0; i < 8; ++i) acc[i] = 0.f;
  for (int ch = 0; ch < 16; ++ch) {
    __syncthreads();
    for (int rr = 0; rr < 32; ++rr)
      s[rr][threadIdx.x] = A[(size_t)(l0 + ch * 32 + rr) * DD + threadIdx.x];
    __syncthreads();
    for (int ll = 0; ll < 32; ++ll) {
      float aj = s[ll][threadIdx.x];
#pragma unroll
      for (int ii = 0; ii < 8; ++ii) acc[ii] += s[ll][i0 + ii] * aj;
    }
  }
#pragma unroll
  for (int ii = 0; ii < 8; ++ii)
    atomicAdd(&G[(size_t)(i0 + ii) * DD + threadIdx.x], acc[ii]);
}

// ------------------- fro[b] = sqrt(sum Gq .* Gk) ---------------------------
__global__ void k_fro(const float* __restrict__ Gq, const float* __restrict__ Gk,
                      float* __restrict__ fro) {
  int b = blockIdx.x;
  const float* gq = Gq + (size_t)b * DD * DD;
  const float* gk = Gk + (size_t)b * DD * DD;
  float acc = 0.f;
  for (int i = threadIdx.x; i < DD * DD; i += 256) acc += gq[i] * gk[i];
#pragma unroll
  for (int m = 32; m; m >>= 1) acc += __shfl_xor(acc, m);
  __shared__ float sbuf[4];
  if ((threadIdx.x & 63) == 0) sbuf[threadIdx.x >> 6] = acc;
  __syncthreads();
  if (threadIdx.x == 0) fro[b] = sqrtf(sbuf[0] + sbuf[1] + sbuf[2] + sbuf[3]);
}

// -------- k_M split-K: Mp[bh][kc] += km[b][rows]^T @ V[bh][rows] -----------
// grid (32 bh, 8 kc, 2 ihalf), block 256. rows = kc*256..+256. No atomics.
__global__ void k_M(const float* __restrict__ km, const float* __restrict__ Vf,
                    float* __restrict__ Mp) {
  int bh = blockIdx.x, b = bh >> 4, kc = blockIdx.y, z = blockIdx.z;
  int l0 = kc * 256;
  __shared__ float skv[16][64];
  __shared__ float sv[16][128];
  int j0 = (threadIdx.x & 31) * 4;
  int i0 = (threadIdx.x >> 5) * 8;
  float acc[8][4];
#pragma unroll
  for (int i = 0; i < 8; ++i)
#pragma unroll
    for (int qq = 0; qq < 4; ++qq) acc[i][qq] = 0.f;
  for (int c = 0; c < 16; ++c) {
    __syncthreads();
    {
      int idx = threadIdx.x;  // 256 float4s for skv (16x64)
      int rr = idx >> 4, c4 = (idx & 15) * 4;
      *(float4*)&skv[rr][c4] =
          *(const float4*)(km + (size_t)(b * LL + l0 + c * 16 + rr) * DD + z * 64 + c4);
#pragma unroll
      for (int x = 0; x < 2; ++x) {
        int id2 = x * 256 + threadIdx.x;  // 512 float4s for sv (16x128)
        int r2 = id2 >> 5, c42 = (id2 & 31) * 4;
        *(float4*)&sv[r2][c42] =
            *(const float4*)(Vf + (size_t)(bh * LL + l0 + c * 16 + r2) * DD + c42);
      }
    }
    __syncthreads();
#pragma unroll
    for (int ll = 0; ll < 16; ++ll) {
      float4 a = *(const float4*)&sv[ll][j0];
      float4 k0 = *(const float4*)&skv[ll][i0];
      float4 k1 = *(const float4*)&skv[ll][i0 + 4];
      float kk[8] = {k0.x, k0.y, k0.z, k0.w, k1.x, k1.y, k1.z, k1.w};
#pragma unroll
      for (int ii = 0; ii < 8; ++ii) {
        acc[ii][0] += kk[ii] * a.x;
        acc[ii][1] += kk[ii] * a.y;
        acc[ii][2] += kk[ii] * a.z;
        acc[ii][3] += kk[ii] * a.w;
      }
    }
  }
  float* dst = Mp + (((size_t)bh * 8 + kc) << 14) + (size_t)(z * 64 + i0) * DD + j0;
#pragma unroll
  for (int ii = 0; ii < 8; ++ii)
    *(float4*)(dst + (size_t)ii * DD) = *(float4*)&acc[ii][0];
}

// -------- reduce 8 partials -> M ------------------------------------------
__global__ void k_Mred(const float* __restrict__ Mp, float* __restrict__ M) {
  int t = blockIdx.x * 256 + threadIdx.x;  // 131072 float4 outputs
  int bh = t >> 12, off = t & 4095;
  const float4* p = (const float4*)Mp;
  float4 s = p[((size_t)bh * 8 + 0) * 4096 + off];
#pragma unroll
  for (int k = 1; k < 8; ++k) {
    float4 v = p[((size_t)bh * 8 + k) * 4096 + off];
    s.x += v.x; s.y += v.y; s.z += v.z; s.w += v.w;
  }
  ((float4*)M)[(size_t)bh * 4096 + off] = s;
}

// -------- legacy atomic k_M for small-ws fallback --------------------------
__global__ void k_M_atomic(const float* __restrict__ km, const float* __restrict__ Vf,
                           float* __restrict__ M) {
  int bh = blockIdx.x, b = bh >> 4;
  int l0 = blockIdx.y * 128;
  __shared__ float skv[16][128];
  __shared__ float sv[16][128];
  int j0 = (threadIdx.x & 31) * 4;
  int i0 = (threadIdx.x >> 5) * 16;
  float acc[16][4];
#pragma unroll
  for (int i = 0; i < 16; ++i)
#pragma unroll
    for (int qq = 0; qq < 4; ++qq) acc[i][qq] = 0.f;
  for (int c = 0; c < 8; ++c) {
    __syncthreads();
    for (int x = 0; x < 8; ++x) {
      int idx = x * 256 + threadIdx.x;
      int rr = idx >> 7, cc = idx & 127;
      skv[rr][cc] = km[(size_t)(b * LL + l0 + c * 16 + rr) * DD + cc];
      sv[rr][cc] = Vf[(size_t)(bh * LL + l0 + c * 16 + rr) * DD + cc];
    }
    __syncthreads();
    for (int ll = 0; ll < 16; ++ll) {
      float a0 = sv[ll][j0], a1 = sv[ll][j0 + 1];
      float a2 = sv[ll][j0 + 2], a3 = sv[ll][j0 + 3];
#pragma unroll
      for (int ii = 0; ii < 16; ++ii) {
        float kv = skv[ll][i0 + ii];
        acc[ii][0] += kv * a0;
        acc[ii][1] += kv * a1;
        acc[ii][2] += kv * a2;
        acc[ii][3] += kv * a3;
      }
    }
  }
#pragma unroll
  for (int ii = 0; ii < 16; ++ii)
#pragma unroll
    for (int qq = 0; qq < 4; ++qq)
      atomicAdd(&M[(size_t)bh * DD * DD + (size_t)(i0 + ii) * DD + j0 + qq],
                acc[ii][qq]);
}

// ---------------- out += q_mult @ M / (fro + eps)  -------------------------
__global__ void k_multadd(const float* __restrict__ qm, const float* __restrict__ M,
                          const float* __restrict__ fro, float* __restrict__ out) {
  int bh = blockIdx.y, b = bh >> 4;
  int l0 = blockIdx.x * 128;
  int row = threadIdx.x & 127, half = threadIdx.x >> 7, dh = half * 64;
  __shared__ float sq[16][129];
  __shared__ float sM[16][128];
  float inv = 1.f / (fro[b] + 1e-5f);
  float acc[64];
#pragma unroll
  for (int i = 0; i < 64; ++i) acc[i] = 0.f;
  for (int c = 0; c < 8; ++c) {
    __syncthreads();
#pragma unroll
    for (int i = 0; i < 2; ++i) {
      int id2 = i * 256 + threadIdx.x;  // 512 iters
      int rr = id2 >> 2, k4 = (id2 & 3) * 4;
      float4 x = *(const float4*)(qm + ((size_t)b * LL + l0 + rr) * DD + c * 16 + k4);
      sq[k4 + 0][rr] = x.x; sq[k4 + 1][rr] = x.y;
      sq[k4 + 2][rr] = x.z; sq[k4 + 3][rr] = x.w;
      int rr2 = id2 >> 5, d4 = (id2 & 31) * 4;
      *(float4*)&sM[rr2][d4] =
          *(const float4*)(M + (size_t)bh * 16384 + (size_t)(c * 16 + rr2) * DD + d4);
    }
    __syncthreads();
#pragma unroll
    for (int kk = 0; kk < 16; ++kk) {
      float qv = sq[kk][row];
      const float4* m4 = (const float4*)&sM[kk][dh];
#pragma unroll
      for (int i = 0; i < 16; ++i) {
        float4 mm = m4[i];
        acc[4 * i + 0] += qv * mm.x;
        acc[4 * i + 1] += qv * mm.y;
        acc[4 * i + 2] += qv * mm.z;
        acc[4 * i + 3] += qv * mm.w;
      }
    }
  }
  float* op = out + ((size_t)bh * LL + l0 + row) * DD + dh;
#pragma unroll
  for (int i = 0; i < 16; ++i) {
    float4 ov = ((float4*)op)[i];
    ov.x += acc[4 * i + 0] * inv;
    ov.y += acc[4 * i + 1] * inv;
    ov.z += acc[4 * i + 2] * inv;
    ov.w += acc[4 * i + 3] * inv;
    ((float4*)op)[i] = ov;
  }
}

// ---------------------------------------------------------------------------
extern "C" void kernel_launch(void* const* d_in, const int* in_sizes, int n_in,
                              void* d_out, int out_size, void* d_ws, size_t ws_size,
                              hipStream_t stream) {
  (void)in_sizes; (void)n_in; (void)out_size;
  const float* Q = (const float*)d_in[0];
  const float* K = (const float*)d_in[1];
  const float* V = (const float*)d_in[2];
  const float* qm = (const float*)d_in[3];
  const float* km = (const float*)d_in[4];
  const int* vl = (const int*)d_in[5];
  float* out = (float*)d_out;

  char* ws = (char*)d_ws;
  const size_t off_M = 0;                      // 2 MB
  const size_t off_Gq = 2097152;
  const size_t off_Gk = off_Gq + 131072;
  const size_t off_fro = off_Gk + 131072;
  const size_t off_Kb = off_fro + 256;         // 16 MB bf16 K tiles
  const size_t szb = (size_t)BH * LL * DD * 2;
  const size_t off_Vt = off_Kb + szb;          // 16 MB bf16 V^T tiles
  const size_t off_end = off_Vt + szb;
  bool fits = ws_size >= off_end;

  float* Mw = (float*)(ws + off_M);
  float* Gq = (float*)(ws + off_Gq);
  float* Gk = (float*)(ws + off_Gk);
  float* fro = (float*)(ws + off_fro);

  // zero G (atomic targets) + M (atomic fallback target)
  hipMemsetAsync(ws + off_M, 0, off_fro + 256, stream);

  k_gram<<<dim3(16, 4, 4), 128, 0, stream>>>(qm, km, Gq, Gk);
  k_fro<<<2, 256, 0, stream>>>(Gq, Gk, fro);

  if (fits) {
    prep_KV<<<2048, 256, 0, stream>>>(K, V, ws + off_Kb, ws + off_Vt);
    k_flash<0><<<dim3(32, 16), 256, 0, stream>>>(ws + off_Kb, ws + off_Vt,
                                                 Q, K, V, vl, out);
    // Kb region dead after k_flash -> reuse as 16 MB split-K partial buffer
    float* Mp = (float*)(ws + off_Kb);
    k_M<<<dim3(32, 8, 2), 256, 0, stream>>>(km, V, Mp);
    k_Mred<<<512, 256, 0, stream>>>(Mp, Mw);
  } else {
    k_flash<1><<<dim3(32, 16), 256, 0, stream>>>(nullptr, nullptr,
                                                 Q, K, V, vl, out);
    k_M_atomic<<<dim3(32, 16), 256, 0, stream>>>(km, V, Mw);
  }
  k_multadd<<<dim3(16, 32), 256, 0, stream>>>(qm, Mw, fro, out);
}

// Round 5
// 173.064 us; speedup vs baseline: 6.2822x; 1.3674x over previous
//
#include <hip/hip_runtime.h>

// ---------------------------------------------------------------------------
// DotProductAttention: out = softmax(mask(Q K^T * scale)) @ V
//                          + (q_mult @ (kv_mult^T @ V)) / (||q_mult kv_mult^T||_F + eps)
// B=2 H=16 BH=32 L=2048 D=128, f32 in/out, bf16 MFMA internally.
// v5: 2-wave flash blocks / KVBLK=32 / grid(qt,bh) for balance; mult term
//     fused into flash epilogue via bf16 M^T; mega-fused pre kernels.
// ---------------------------------------------------------------------------

typedef __attribute__((ext_vector_type(8))) __bf16 bf16x8;
typedef __attribute__((ext_vector_type(16))) float f32x16;
typedef __attribute__((ext_vector_type(4))) unsigned int u32x4;

#define DEV static __device__ __forceinline__

constexpr int LL = 2048, DD = 128, BH = 32;
constexpr float SCALE = 0.08838834764831845f;  // 1/sqrt(128)
constexpr float NEGV = -1e6f;

DEV unsigned pkb(float a, float b) {  // pack two f32 -> bf16x2
  union { __bf16 h[2]; unsigned u; } x;
  x.h[0] = (__bf16)a; x.h[1] = (__bf16)b;
  return x.u;
}
DEV f32x16 mfma32(bf16x8 a, bf16x8 b, f32x16 c) {
  return __builtin_amdgcn_mfma_f32_32x32x16_bf16(a, b, c, 0, 0, 0);
}
DEV void gl16(const void* g, void* l) {
  __builtin_amdgcn_global_load_lds(
      (const __attribute__((address_space(1))) unsigned int*)g,
      (__attribute__((address_space(3))) unsigned int*)l, 16, 0, 0);
}

// ---------------------------------------------------------------------------
// mega_pre: [0,512) k_M split-8 partials -> Mp (in d_out)
//           [512,640) gram atomics -> Gq/Gk
//           [640,1664) prep K -> bf16 swizzled 8KB tiles (bh, kt32)
//           [1664,3712) prep V -> bf16 [d][k] swizzled 8KB tiles (bh, kt32)
// K tile byte(kk,d8) = kk*256 + ((d8 ^ (kk&15))<<4)
// V tile byte(d,kk)  = d*64 + (((kk>>3) ^ ((d>>1)&3))<<4) + (kk&7)*2
// ---------------------------------------------------------------------------
__global__ __launch_bounds__(256)
void mega_pre(const float* __restrict__ K, const float* __restrict__ V,
              const float* __restrict__ qm, const float* __restrict__ km,
              char* __restrict__ Kb, char* __restrict__ Vt,
              float* __restrict__ Gq, float* __restrict__ Gk,
              float* __restrict__ Mp) {
  __shared__ __align__(16) char smem[16384];
  const int bx = blockIdx.x, tid = threadIdx.x;

  if (bx < 512) {  // ---- k_M split-8: 256 rows of km^T @ V ----
    float (*skv)[64] = (float(*)[64])smem;           // 4KB
    float (*sv)[128] = (float(*)[128])(smem + 4096); // 8KB
    int bh = bx & 31, b = bh >> 4, kc = (bx >> 5) & 7, z = (bx >> 8) & 1;
    int l0 = kc * 256;
    int j0 = (tid & 31) * 4, i0 = (tid >> 5) * 8;
    float acc[8][4];
#pragma unroll
    for (int i = 0; i < 8; ++i)
#pragma unroll
      for (int qq = 0; qq < 4; ++qq) acc[i][qq] = 0.f;
    for (int c = 0; c < 16; ++c) {
      __syncthreads();
      {
        int rr = tid >> 4, c4 = (tid & 15) * 4;
        *(float4*)&skv[rr][c4] =
            *(const float4*)(km + (size_t)(b * LL + l0 + c * 16 + rr) * DD + z * 64 + c4);
#pragma unroll
        for (int x = 0; x < 2; ++x) {
          int id2 = x * 256 + tid;
          int r2 = id2 >> 5, c42 = (id2 & 31) * 4;
          *(float4*)&sv[r2][c42] =
              *(const float4*)(V + (size_t)(bh * LL + l0 + c * 16 + r2) * DD + c42);
        }
      }
      __syncthreads();
#pragma unroll
      for (int ll = 0; ll < 16; ++ll) {
        float4 a = *(const float4*)&sv[ll][j0];
        float4 k0 = *(const float4*)&skv[ll][i0];
        float4 k1 = *(const float4*)&skv[ll][i0 + 4];
        float kk[8] = {k0.x, k0.y, k0.z, k0.w, k1.x, k1.y, k1.z, k1.w};
#pragma unroll
        for (int ii = 0; ii < 8; ++ii) {
          acc[ii][0] += kk[ii] * a.x;
          acc[ii][1] += kk[ii] * a.y;
          acc[ii][2] += kk[ii] * a.z;
          acc[ii][3] += kk[ii] * a.w;
        }
      }
    }
    float* dst = Mp + (((size_t)bh * 8 + kc) << 14) + (size_t)(z * 64 + i0) * 128 + j0;
#pragma unroll
    for (int ii = 0; ii < 8; ++ii)
      *(float4*)(dst + (size_t)ii * 128) = *(float4*)&acc[ii][0];

  } else if (bx < 640) {  // ---- gram ----
    float (*s)[128] = (float(*)[128])smem;  // 16KB
    int g = bx - 512;
    int ib = g & 7, lc = (g >> 3) & 3, wb = g >> 5;
    int which = wb >> 1, b = wb & 1;
    const float* A = (which ? km : qm) + (size_t)b * LL * DD;
    float* G = (which ? Gk : Gq) + (size_t)b * DD * DD;
    int i0 = ib * 16 + (tid >> 7) * 8, j = tid & 127;
    int l0 = lc * 512;
    float acc[8];
#pragma unroll
    for (int i = 0; i < 8; ++i) acc[i] = 0.f;
    for (int ch = 0; ch < 16; ++ch) {
      __syncthreads();
#pragma unroll
      for (int i = 0; i < 4; ++i) {
        int c = i * 256 + tid;
        int row = c >> 5, c4 = (c & 31) * 4;
        *(float4*)&s[row][c4] =
            *(const float4*)(A + (size_t)(l0 + ch * 32 + row) * DD + c4);
      }
      __syncthreads();
#pragma unroll
      for (int ll = 0; ll < 32; ++ll) {
        float aj = s[ll][j];
#pragma unroll
        for (int ii = 0; ii < 8; ++ii) acc[ii] += s[ll][i0 + ii] * aj;
      }
    }
#pragma unroll
    for (int ii = 0; ii < 8; ++ii)
      atomicAdd(&G[(size_t)(i0 + ii) * DD + j], acc[ii]);

  } else if (bx < 1664) {  // ---- prep K ----
    int pk = bx - 640;
#pragma unroll
    for (int i = 0; i < 4; ++i) {
      int cid = i * 262144 + pk * 256 + tid;
      int h = cid >> 15, k = (cid >> 4) & 2047, c = cid & 15;
      const float* p = K + ((size_t)h * LL + k) * DD + c * 8;
      float4 x0 = *(const float4*)p, x1 = *(const float4*)(p + 4);
      u32x4 v;
      v.x = pkb(x0.x, x0.y); v.y = pkb(x0.z, x0.w);
      v.z = pkb(x1.x, x1.y); v.w = pkb(x1.z, x1.w);
      char* dst = Kb + (((size_t)h * 64 + (k >> 5)) << 13) + ((k & 31) << 8) +
                  ((c ^ (k & 15)) << 4);
      *(u32x4*)dst = v;
    }

  } else {  // ---- prep V ----
    float (*sV)[128] = (float(*)[128])smem;  // 16KB (32 rows)
    int pv = bx - 1664;
    int h = pv >> 6, kt = pv & 63;
    const float* src = V + ((size_t)h * LL + kt * 32) * DD;
#pragma unroll
    for (int i = 0; i < 4; ++i) {
      int c = i * 256 + tid;
      int row = c >> 5, c4 = (c & 31) * 4;
      *(float4*)&sV[row][c4] = *(const float4*)(src + (size_t)row * DD + c4);
    }
    __syncthreads();
    char* dstb = Vt + (((size_t)h * 64 + kt) << 13);
#pragma unroll
    for (int i = 0; i < 2; ++i) {
      int c = i * 256 + tid;
      int d = c >> 2, kk8 = c & 3;
      u32x4 v;
      v.x = pkb(sV[kk8 * 8 + 0][d], sV[kk8 * 8 + 1][d]);
      v.y = pkb(sV[kk8 * 8 + 2][d], sV[kk8 * 8 + 3][d]);
      v.z = pkb(sV[kk8 * 8 + 4][d], sV[kk8 * 8 + 5][d]);
      v.w = pkb(sV[kk8 * 8 + 6][d], sV[kk8 * 8 + 7][d]);
      *(u32x4*)(dstb + d * 64 + ((kk8 ^ ((d >> 1) & 3)) << 4)) = v;
    }
  }
}

// ---------------------------------------------------------------------------
// k_post: bx<2 -> fro[b]; bx>=2 -> reduce 8 Mp partials, write bf16 M^T
// M^T tile per bh (32KB): byte(d,k) = d*256 + (((k>>3) ^ (d&15))<<4) + (k&7)*2
// ---------------------------------------------------------------------------
__global__ __launch_bounds__(256)
void k_post(const float* __restrict__ Gq, const float* __restrict__ Gk,
            float* __restrict__ fro, const float* __restrict__ Mp,
            char* __restrict__ MT) {
  int bx = blockIdx.x, tid = threadIdx.x;
  if (bx < 2) {
    int b = bx;
    const float* gq = Gq + (size_t)b * DD * DD;
    const float* gk = Gk + (size_t)b * DD * DD;
    float acc = 0.f;
    for (int i = tid; i < DD * DD; i += 256) acc += gq[i] * gk[i];
#pragma unroll
    for (int m = 32; m; m >>= 1) acc += __shfl_xor(acc, m);
    __shared__ float sbuf[4];
    if ((tid & 63) == 0) sbuf[tid >> 6] = acc;
    __syncthreads();
    if (tid == 0) fro[b] = sqrtf(sbuf[0] + sbuf[1] + sbuf[2] + sbuf[3]);
  } else {
    int g = bx - 2;
    int bh = g >> 2, kq = (g & 3) * 32;
    int k = kq + (tid >> 3), d0 = (tid & 7) * 16;
    float acc[16];
#pragma unroll
    for (int i = 0; i < 16; ++i) acc[i] = 0.f;
#pragma unroll
    for (int s = 0; s < 8; ++s) {
      const float* p = Mp + (((size_t)bh * 8 + s) << 14) + (size_t)k * 128 + d0;
#pragma unroll
      for (int i = 0; i < 4; ++i) {
        float4 v = *(const float4*)(p + i * 4);
        acc[4 * i + 0] += v.x; acc[4 * i + 1] += v.y;
        acc[4 * i + 2] += v.z; acc[4 * i + 3] += v.w;
      }
    }
    char* dst = MT + (size_t)bh * 32768;
#pragma unroll
    for (int j = 0; j < 16; ++j) {
      int d = d0 + j;
      union { __bf16 h; unsigned short u; } cv;
      cv.h = (__bf16)acc[j];
      *(unsigned short*)(dst + d * 256 + (((k >> 3) ^ (d & 15)) << 4) + (k & 7) * 2) = cv.u;
    }
  }
}

// ---------------------------------------------------------------------------
// flash: grid (32 qt, 32 bh), block 128 (2 waves x 32 q-rows), KVBLK=32.
// MODE0: prepped tiles + global_load_lds dbuf; fused mult-term epilogue.
// MODE1: fallback, stage from f32 inline; attn only.
// ---------------------------------------------------------------------------
template <int MODE>
__global__ __launch_bounds__(128, 2)
void k_flash(const char* __restrict__ KbG, const char* __restrict__ VtG,
             const char* __restrict__ MT, const float* __restrict__ fro,
             const float* __restrict__ Qf, const float* __restrict__ Kf,
             const float* __restrict__ Vf, const float* __restrict__ qmf,
             const int* __restrict__ vl, float* __restrict__ out) {
  __shared__ __align__(16) char lds[MODE ? 16384 : 32768];

  const int qt = blockIdx.x, bh = blockIdx.y, b = bh >> 4;
  const int tid = threadIdx.x, w = tid >> 6, lane = tid & 63;
  const int r32 = lane & 31, hi = lane >> 5;
  const int vlen = vl[bh];
  const size_t base = (size_t)bh * LL * DD;
  const int q = qt * 64 + w * 32 + r32;

  // Q fragments (B-operand: col=q, k=ks*16+hi*8+j), pre-scaled by 1/sqrt(d)
  bf16x8 qfr[8];
#pragma unroll
  for (int ks = 0; ks < 8; ++ks) {
    const float* p = Qf + base + (size_t)q * DD + ks * 16 + hi * 8;
    float4 x0 = *(const float4*)p, x1 = *(const float4*)(p + 4);
    union { unsigned u[4]; bf16x8 v; } u;
    u.u[0] = pkb(x0.x * SCALE, x0.y * SCALE);
    u.u[1] = pkb(x0.z * SCALE, x0.w * SCALE);
    u.u[2] = pkb(x1.x * SCALE, x1.y * SCALE);
    u.u[3] = pkb(x1.z * SCALE, x1.w * SCALE);
    qfr[ks] = u.v;
  }

  f32x16 o[4];
#pragma unroll
  for (int dt = 0; dt < 4; ++dt)
#pragma unroll
    for (int e = 0; e < 16; ++e) o[dt][e] = 0.f;
  float mrun = -3e38f, lrun = 0.f;

  int nt = (vlen == 0) ? 64 : ((vlen + 31) >> 5);

  auto compute = [&](const char* Kl, const char* Vl, int kbase) {
    f32x16 s0;
#pragma unroll
    for (int e = 0; e < 16; ++e) s0[e] = 0.f;
    __builtin_amdgcn_s_setprio(1);
#pragma unroll
    for (int ks = 0; ks < 8; ++ks) {
      bf16x8 a0 = *(const bf16x8*)(Kl + r32 * 256 + (((2 * ks + hi) ^ (r32 & 15)) << 4));
      s0 = mfma32(a0, qfr[ks], s0);
    }
    __builtin_amdgcn_s_setprio(0);

    if (kbase + 32 > vlen) {
#pragma unroll
      for (int e = 0; e < 16; ++e) {
        int k0 = kbase + (e & 3) + 8 * (e >> 2) + 4 * hi;
        if (k0 >= vlen) s0[e] = NEGV;
      }
    }
    f32x16 mx = s0;
#pragma unroll
    for (int st = 8; st; st >>= 1)
#pragma unroll
      for (int e = 0; e < st; ++e) mx[e] = fmaxf(mx[e], mx[e + st]);
    float pm = fmaxf(mx[0], __shfl_xor(mx[0], 32));

    if (!__all(pm <= mrun + 8.f)) {  // defer-max (T13)
      float mn = fmaxf(mrun, pm);
      float al = __expf(mrun - mn);
      lrun *= al;
#pragma unroll
      for (int dt = 0; dt < 4; ++dt)
#pragma unroll
        for (int e = 0; e < 16; ++e) o[dt][e] *= al;
      mrun = mn;
    }
#pragma unroll
    for (int e = 0; e < 16; ++e) s0[e] = __expf(s0[e] - mrun);
    f32x16 sm = s0;
#pragma unroll
    for (int st = 8; st; st >>= 1)
#pragma unroll
      for (int e = 0; e < st; ++e) sm[e] += sm[e + st];
    lrun += sm[0];

    // pack P -> bf16 B-frags (exchange halves via shfl_xor 32)
    bf16x8 PA[2];
#pragma unroll
    for (int ks = 0; ks < 2; ++ks) {
      int bb = ks * 8;
      unsigned x1 = pkb(s0[bb + 0], s0[bb + 1]);
      unsigned x2 = pkb(s0[bb + 2], s0[bb + 3]);
      unsigned y1 = pkb(s0[bb + 4], s0[bb + 5]);
      unsigned y2 = pkb(s0[bb + 6], s0[bb + 7]);
      unsigned sx1 = __shfl_xor(x1, 32), sx2 = __shfl_xor(x2, 32);
      unsigned sy1 = __shfl_xor(y1, 32), sy2 = __shfl_xor(y2, 32);
      union { unsigned u[4]; bf16x8 v; } pu;
      pu.u[0] = hi ? sy1 : x1;
      pu.u[1] = hi ? sy2 : x2;
      pu.u[2] = hi ? y1 : sx1;
      pu.u[3] = hi ? y2 : sx2;
      PA[ks] = pu.v;
    }
    __builtin_amdgcn_s_setprio(1);
#pragma unroll
    for (int dt = 0; dt < 4; ++dt)
#pragma unroll
      for (int ks = 0; ks < 2; ++ks) {
        bf16x8 av = *(const bf16x8*)(Vl + (dt * 32 + r32) * 64 +
                                     (((2 * ks + hi) ^ ((r32 >> 1) & 3)) << 4));
        o[dt] = mfma32(av, PA[ks], o[dt]);
      }
    __builtin_amdgcn_s_setprio(0);
  };

  if (MODE == 0) {
    auto stage = [&](int t, int c2) {
      const char* gk = KbG + (((size_t)bh * 64 + t) << 13) + tid * 16;
      const char* gv = VtG + (((size_t)bh * 64 + t) << 13) + tid * 16;
      char* lk = lds + c2 * 16384 + tid * 16;
      char* lv = lds + c2 * 16384 + 8192 + tid * 16;
#pragma unroll
      for (int i = 0; i < 4; ++i) {
        gl16(gk + i * 2048, lk + i * 2048);
        gl16(gv + i * 2048, lv + i * 2048);
      }
    };
    stage(0, 0);
    __syncthreads();
    int cur = 0;
    for (int t = 0; t < nt; ++t) {
      if (t + 1 < nt) stage(t + 1, cur ^ 1);  // prefetch hides under compute
      compute(lds + cur * 16384, lds + cur * 16384 + 8192, t * 32);
      __syncthreads();
      cur ^= 1;
    }
  } else {
    char* Kl = lds;
    char* Vl = lds + 8192;
    for (int t = 0; t < nt; ++t) {
      int kbase = t * 32;
#pragma unroll
      for (int i = 0; i < 4; ++i) {
        int c = i * 128 + tid;
        int kk = c >> 4, sl = c & 15;
        const float* p = Kf + base + (size_t)(kbase + kk) * DD + sl * 8;
        float4 x0 = *(const float4*)p, x1 = *(const float4*)(p + 4);
        u32x4 v;
        v.x = pkb(x0.x, x0.y); v.y = pkb(x0.z, x0.w);
        v.z = pkb(x1.x, x1.y); v.w = pkb(x1.z, x1.w);
        *(u32x4*)(Kl + (kk << 8) + ((sl ^ (kk & 15)) << 4)) = v;
      }
#pragma unroll
      for (int i = 0; i < 4; ++i) {
        int c = i * 128 + tid;
        int d = c >> 2, kk8 = c & 3;
        float t0[8];
#pragma unroll
        for (int j = 0; j < 8; ++j)
          t0[j] = Vf[base + (size_t)(kbase + kk8 * 8 + j) * DD + d];
        u32x4 v;
        v.x = pkb(t0[0], t0[1]); v.y = pkb(t0[2], t0[3]);
        v.z = pkb(t0[4], t0[5]); v.w = pkb(t0[6], t0[7]);
        *(u32x4*)(Vl + d * 64 + ((kk8 ^ ((d >> 1) & 3)) << 4)) = v;
      }
      __syncthreads();
      compute(Kl, Vl, kbase);
      __syncthreads();
    }
  }

  // ---- epilogue: normalize attn; fused mult term (MODE 0) ----
  float lt = lrun + __shfl_xor(lrun, 32);
  float inv = 1.f / lt;
#pragma unroll
  for (int dt = 0; dt < 4; ++dt)
#pragma unroll
    for (int e = 0; e < 16; ++e) o[dt][e] *= inv;

  if (MODE == 0) {
    float invf = 1.f / (fro[b] + 1e-5f);
    bf16x8 qb[8];
#pragma unroll
    for (int ks = 0; ks < 8; ++ks) {
      const float* p = qmf + ((size_t)b * LL + q) * DD + ks * 16 + hi * 8;
      float4 x0 = *(const float4*)p, x1 = *(const float4*)(p + 4);
      union { unsigned u[4]; bf16x8 v; } u;
      u.u[0] = pkb(x0.x * invf, x0.y * invf);
      u.u[1] = pkb(x0.z * invf, x0.w * invf);
      u.u[2] = pkb(x1.x * invf, x1.y * invf);
      u.u[3] = pkb(x1.z * invf, x1.w * invf);
      qb[ks] = u.v;
    }
    const char* MTb = MT + (size_t)bh * 32768;
#pragma unroll
    for (int kc = 0; kc < 8; ++kc)
#pragma unroll
      for (int dt = 0; dt < 4; ++dt) {
        bf16x8 av = *(const bf16x8*)(MTb + (dt * 32 + r32) * 256 +
                                     (((2 * kc + hi) ^ (r32 & 15)) << 4));
        o[dt] = mfma32(av, qb[kc], o[dt]);
      }
  }

  float* op = out + base + (size_t)q * DD;
#pragma unroll
  for (int dt = 0; dt < 4; ++dt)
#pragma unroll
    for (int rq = 0; rq < 4; ++rq) {
      float4 v;
      v.x = o[dt][4 * rq + 0];
      v.y = o[dt][4 * rq + 1];
      v.z = o[dt][4 * rq + 2];
      v.w = o[dt][4 * rq + 3];
      *(float4*)(op + dt * 32 + rq * 8 + hi * 4) = v;
    }
}

// ------------------- fallback-only kernels ---------------------------------
__global__ void k_gram(const float* __restrict__ qm, const float* __restrict__ km,
                       float* __restrict__ Gq, float* __restrict__ Gk) {
  int which = blockIdx.z >> 1, b = blockIdx.z & 1;
  const float* A = (which ? km : qm) + (size_t)b * LL * DD;
  float* G = (which ? Gk : Gq) + (size_t)b * DD * DD;
  int i0 = blockIdx.x * 8;
  int l0 = blockIdx.y * 512;
  __shared__ float s[32][128];
  float acc[8];
#pragma unroll
  for (int i = 0; i < 8; ++i) acc[i] = 0.f;
  for (int ch = 0; ch < 16; ++ch) {
    __syncthreads();
    for (int rr = 0; rr < 32; ++rr)
      s[rr][threadIdx.x] = A[(size_t)(l0 + ch * 32 + rr) * DD + threadIdx.x];
    __syncthreads();
    for (int ll = 0; ll < 32; ++ll) {
      float aj = s[ll][threadIdx.x];
#pragma unroll
      for (int ii = 0; ii < 8; ++ii) acc[ii] += s[ll][i0 + ii] * aj;
    }
  }
#pragma unroll
  for (int ii = 0; ii < 8; ++ii)
    atomicAdd(&G[(size_t)(i0 + ii) * DD + threadIdx.x], acc[ii]);
}

__global__ void k_fro(const float* __restrict__ Gq, const float* __restrict__ Gk,
                      float* __restrict__ fro) {
  int b = blockIdx.x;
  const float* gq = Gq + (size_t)b * DD * DD;
  const float* gk = Gk + (size_t)b * DD * DD;
  float acc = 0.f;
  for (int i = threadIdx.x; i < DD * DD; i += 256) acc += gq[i] * gk[i];
#pragma unroll
  for (int m = 32; m; m >>= 1) acc += __shfl_xor(acc, m);
  __shared__ float sbuf[4];
  if ((threadIdx.x & 63) == 0) sbuf[threadIdx.x >> 6] = acc;
  __syncthreads();
  if (threadIdx.x == 0) fro[b] = sqrtf(sbuf[0] + sbuf[1] + sbuf[2] + sbuf[3]);
}

__global__ void k_M_atomic(const float* __restrict__ km, const float* __restrict__ Vf,
                           float* __restrict__ M) {
  int bh = blockIdx.x, b = bh >> 4;
  int l0 = blockIdx.y * 128;
  __shared__ float skv[16][128];
  __shared__ float sv[16][128];
  int j0 = (threadIdx.x & 31) * 4;
  int i0 = (threadIdx.x >> 5) * 16;
  float acc[16][4];
#pragma unroll
  for (int i = 0; i < 16; ++i)
#pragma unroll
    for (int qq = 0; qq < 4; ++qq) acc[i][qq] = 0.f;
  for (int c = 0; c < 8; ++c) {
    __syncthreads();
    for (int x = 0; x < 8; ++x) {
      int idx = x * 256 + threadIdx.x;
      int rr = idx >> 7, cc = idx & 127;
      skv[rr][cc] = km[(size_t)(b * LL + l0 + c * 16 + rr) * DD + cc];
      sv[rr][cc] = Vf[(size_t)(bh * LL + l0 + c * 16 + rr) * DD + cc];
    }
    __syncthreads();
    for (int ll = 0; ll < 16; ++ll) {
      float a0 = sv[ll][j0], a1 = sv[ll][j0 + 1];
      float a2 = sv[ll][j0 + 2], a3 = sv[ll][j0 + 3];
#pragma unroll
      for (int ii = 0; ii < 16; ++ii) {
        float kv = skv[ll][i0 + ii];
        acc[ii][0] += kv * a0;
        acc[ii][1] += kv * a1;
        acc[ii][2] += kv * a2;
        acc[ii][3] += kv * a3;
      }
    }
  }
#pragma unroll
  for (int ii = 0; ii < 16; ++ii)
#pragma unroll
    for (int qq = 0; qq < 4; ++qq)
      atomicAdd(&M[(size_t)bh * DD * DD + (size_t)(i0 + ii) * DD + j0 + qq],
                acc[ii][qq]);
}

__global__ void k_multadd(const float* __restrict__ qm, const float* __restrict__ M,
                          const float* __restrict__ fro, float* __restrict__ out) {
  int bh = blockIdx.y, b = bh >> 4;
  int l = blockIdx.x * 128 + (threadIdx.x & 127);
  int dh = (threadIdx.x >> 7) * 64;
  float inv = 1.0f / (fro[b] + 1e-5f);
  const float* qrow = qm + ((size_t)b * LL + l) * DD;
  const float* Mb = M + (size_t)bh * DD * DD + dh;
  float acc[64];
#pragma unroll
  for (int i = 0; i < 64; ++i) acc[i] = 0.f;
  for (int k = 0; k < 128; ++k) {
    float qv = qrow[k];
    const float4* m4 = (const float4*)(Mb + (size_t)k * DD);
#pragma unroll
    for (int i = 0; i < 16; ++i) {
      float4 mm = m4[i];
      acc[4 * i + 0] += qv * mm.x;
      acc[4 * i + 1] += qv * mm.y;
      acc[4 * i + 2] += qv * mm.z;
      acc[4 * i + 3] += qv * mm.w;
    }
  }
  float* op = out + ((size_t)bh * LL + l) * DD + dh;
#pragma unroll
  for (int i = 0; i < 16; ++i) {
    float4 ov = ((float4*)op)[i];
    ov.x += acc[4 * i + 0] * inv;
    ov.y += acc[4 * i + 1] * inv;
    ov.z += acc[4 * i + 2] * inv;
    ov.w += acc[4 * i + 3] * inv;
    ((float4*)op)[i] = ov;
  }
}

// ---------------------------------------------------------------------------
extern "C" void kernel_launch(void* const* d_in, const int* in_sizes, int n_in,
                              void* d_out, int out_size, void* d_ws, size_t ws_size,
                              hipStream_t stream) {
  (void)in_sizes; (void)n_in; (void)out_size;
  const float* Q = (const float*)d_in[0];
  const float* K = (const float*)d_in[1];
  const float* V = (const float*)d_in[2];
  const float* qm = (const float*)d_in[3];
  const float* km = (const float*)d_in[4];
  const int* vl = (const int*)d_in[5];
  float* out = (float*)d_out;

  char* ws = (char*)d_ws;
  const size_t off_Gq = 0;                       // 128 KB
  const size_t off_Gk = 131072;                  // 128 KB
  const size_t off_fro = 262144;                 // 256 B
  const size_t off_MT = 294912;                  // 1 MB bf16 M^T tiles
  const size_t off_Kb = off_MT + 1048576;        // 16 MB bf16 K tiles
  const size_t szb = (size_t)BH * LL * DD * 2;
  const size_t off_Vt = off_Kb + szb;            // 16 MB bf16 V^T tiles
  const size_t off_end = off_Vt + szb;           // ~33.3 MB total
  bool fits = ws_size >= off_end;

  float* Gq = (float*)(ws + off_Gq);
  float* Gk = (float*)(ws + off_Gk);
  float* fro = (float*)(ws + off_fro);
  char* MT = ws + off_MT;

  if (fits) {
    float* Mp = (float*)d_out;  // 16 MB split-K partials live in out (dead until flash)
    hipMemsetAsync(ws, 0, off_fro + 256, stream);
    mega_pre<<<3712, 256, 0, stream>>>(K, V, qm, km, ws + off_Kb, ws + off_Vt,
                                       Gq, Gk, Mp);
    k_post<<<130, 256, 0, stream>>>(Gq, Gk, fro, Mp, MT);
    k_flash<0><<<dim3(32, 32), 128, 0, stream>>>(ws + off_Kb, ws + off_Vt, MT, fro,
                                                 Q, K, V, qm, vl, out);
  } else {
    float* Mw = (float*)(ws + off_MT);  // 2 MB f32 M (fallback only)
    hipMemsetAsync(ws, 0, off_MT + 2097152, stream);
    k_gram<<<dim3(16, 4, 4), 128, 0, stream>>>(qm, km, Gq, Gk);
    k_fro<<<2, 256, 0, stream>>>(Gq, Gk, fro);
    k_flash<1><<<dim3(32, 32), 128, 0, stream>>>(nullptr, nullptr, nullptr, nullptr,
                                                 Q, K, V, qm, vl, out);
    k_M_atomic<<<dim3(32, 16), 256, 0, stream>>>(km, V, Mw);
    k_multadd<<<dim3(16, 32), 256, 0, stream>>>(qm, Mw, fro, out);
  }
}